// Round 5
// baseline (1498.532 us; speedup 1.0000x reference)
//
#include <hip/hip_runtime.h>
#include <hip/hip_bf16.h>

typedef short short8 __attribute__((ext_vector_type(8)));
typedef float floatx4 __attribute__((ext_vector_type(4)));

#define SCALE_F 0.10206207261596575f

static __device__ __forceinline__ float b2f(unsigned short u){
  unsigned int v = ((unsigned int)u) << 16; float f;
  __builtin_memcpy(&f, &v, 4); return f;
}
static __device__ __forceinline__ unsigned short f2b(float f){
  __hip_bfloat16 h = __float2bfloat16(f);
  unsigned short u; __builtin_memcpy(&u, &h, 2); return u;
}

struct ConvDesc {
  const void* src[17];
  long long off[17];
  int count[17];
};

// ---------------- K0: dtype detect + convert all float tensors to bf16 ----------------
__global__ __launch_bounds__(256) void k_convert(ConvDesc d, unsigned short* dst_base,
                                                 int* flagp, const unsigned int* xprobe)
{
  __shared__ int sflag;
  if (threadIdx.x < 64){
    unsigned int w = xprobe[1024 + threadIdx.x];
    int e = (w >> 7) & 0xFF;           // exponent of LOW ushort viewed as bf16
    int pl = (e >= 90 && e <= 140) ? 1 : 0;
    unsigned long long m = __ballot(pl);
    if (threadIdx.x == 0){
      sflag = (__popcll(m) < 40) ? 1 : 0;   // 1 = inputs are fp32
      if (blockIdx.x == 0 && blockIdx.y == 0) *flagp = sflag;
    }
  }
  __syncthreads();
  const int flag = sflag;
  const int t = blockIdx.y;
  const int cnt = d.count[t];
  unsigned short* dst = dst_base + d.off[t];
  const float* sf = (const float*)d.src[t];
  const unsigned short* su = (const unsigned short*)d.src[t];
  for (int i = blockIdx.x*blockDim.x + threadIdx.x; i < cnt; i += gridDim.x*blockDim.x){
    dst[i] = flag ? f2b(sf[i]) : su[i];
  }
}

// ---------------- K1: QKV GEMM (x read once per row-tile; all 576 cols per block) ------
__global__ __launch_bounds__(256) void k_qkv(
    const unsigned short* __restrict__ x, const unsigned short* __restrict__ w,
    const unsigned short* __restrict__ bias,
    unsigned short* __restrict__ qr, unsigned short* __restrict__ kr, unsigned short* __restrict__ vr)
{
  const int lane = threadIdx.x & 63;
  const int wv = threadIdx.x >> 6;
  const int kq = (lane >> 4) * 8;
  const int m_base = blockIdx.x * 64 + wv * 16;   // this wave's 16 rows

  int ma = m_base + (lane & 15); if (ma > 100355) ma = 100355;
  const unsigned short* xrow = x + (size_t)ma*96 + kq;
  short8 a0 = *(const short8*)(xrow);
  short8 a1 = *(const short8*)(xrow + 32);
  short8 a2 = *(const short8*)(xrow + 64);

  size_t base0[4];
  int mrow[4];
  #pragma unroll
  for (int r = 0; r < 4; ++r){
    int m = m_base + (lane >> 4)*4 + r;
    mrow[r] = m;
    int bb = m / 25089; int n = m - bb*25089;
    base0[r] = ((size_t)(bb*2)*25089 + n)*96;
  }

  for (int ct = 0; ct < 36; ++ct){
    int col = ct*16 + (lane & 15);
    const unsigned short* wrow = w + col*96 + kq;
    short8 b0 = *(const short8*)(wrow);
    short8 b1 = *(const short8*)(wrow + 32);
    short8 b2 = *(const short8*)(wrow + 64);
    float bv = b2f(bias[col]);
    floatx4 acc = {0.f,0.f,0.f,0.f};
    acc = __builtin_amdgcn_mfma_f32_16x16x32_bf16(a0, b0, acc, 0,0,0);
    acc = __builtin_amdgcn_mfma_f32_16x16x32_bf16(a1, b1, acc, 0,0,0);
    acc = __builtin_amdgcn_mfma_f32_16x16x32_bf16(a2, b2, acc, 0,0,0);
    int which = col / 192; int rem = col - which*192; int head = rem / 96; int d = rem - head*96;
    unsigned short* ob = (which == 0) ? qr : ((which == 1) ? kr : vr);
    size_t hoff = (size_t)head * 2408544 + d;
    #pragma unroll
    for (int r = 0; r < 4; ++r){
      if (mrow[r] < 100356) ob[base0[r] + hoff] = f2b(acc[r] + bv);
    }
  }
}

// ---------------- K2: q pooling (stride 1,2,2) + LN — tile-based, vectorized ----------
__global__ __launch_bounds__(384) void k_poolq(
    const unsigned short* __restrict__ qr, const unsigned short* __restrict__ cw,
    const unsigned short* __restrict__ g, const unsigned short* __restrict__ bta,
    unsigned short* __restrict__ qp)
{
  __shared__ float wlds[27*96];
  __shared__ float gls[96], bls[96];
  __shared__ float ls1[29*12], ls2[29*12];
  __shared__ float lmean[29], linv[29];

  const int y  = blockIdx.x;
  const int t  = blockIdx.y;
  const int bh = blockIdx.z;
  const int tid = threadIdx.x;
  const bool has_cls = (y == 0 && t == 0);
  const unsigned short* base = qr + (size_t)bh*2408544;

  for (int idx = tid; idx < 27*96; idx += 384){
    int tap = idx / 96, d = idx - tap*96;
    wlds[idx] = b2f(cw[d*27 + tap]);
  }
  for (int idx = tid; idx < 96; idx += 384){
    gls[idx] = b2f(g[idx]); bls[idx] = b2f(bta[idx]);
  }
  __syncthreads();

  const int x = tid / 12, dg = tid - x*12;
  float val[8] = {0,0,0,0,0,0,0,0};

  if (x < 28){
    #pragma unroll
    for (int dt = 0; dt < 3; ++dt){
      int tt = t + dt - 1; if (tt < 0 || tt >= 8) continue;
      #pragma unroll
      for (int dy = 0; dy < 3; ++dy){
        int yy = 2*y + dy - 1; if (yy < 0 || yy >= 56) continue;
        #pragma unroll
        for (int dx = 0; dx < 3; ++dx){
          int xv = 2*x + dx - 1; if (xv < 0 || xv >= 56) continue;
          const int tap = (dt*3+dy)*3+dx;
          short8 v = *(const short8*)(base + (size_t)(1 + (tt*56 + yy)*56 + xv)*96 + dg*8);
          const float* wr = wlds + tap*96 + dg*8;
          #pragma unroll
          for (int j = 0; j < 8; ++j) val[j] += b2f((unsigned short)v[j]) * wr[j];
        }
      }
    }
    float s1 = 0.f, s2 = 0.f;
    #pragma unroll
    for (int j = 0; j < 8; ++j){ s1 += val[j]; s2 += val[j]*val[j]; }
    ls1[x*12+dg] = s1; ls2[x*12+dg] = s2;
  } else if (has_cls && tid >= 348 && tid < 360){
    int cdg = tid - 348;
    short8 v = *(const short8*)(base + cdg*8);
    float s1 = 0.f, s2 = 0.f;
    #pragma unroll
    for (int j = 0; j < 8; ++j){ val[j] = b2f((unsigned short)v[j]); s1 += val[j]; s2 += val[j]*val[j]; }
    ls1[28*12+cdg] = s1; ls2[28*12+cdg] = s2;
  }
  __syncthreads();

  if (tid < 28 || (tid == 28 && has_cls)){
    float s1 = 0.f, s2 = 0.f;
    #pragma unroll
    for (int k = 0; k < 12; ++k){ s1 += ls1[tid*12+k]; s2 += ls2[tid*12+k]; }
    float mean = s1 * (1.f/96.f);
    float var  = s2 * (1.f/96.f) - mean*mean;
    lmean[tid] = mean; linv[tid] = rsqrtf(var + 1e-5f);
  }
  __syncthreads();

  if (x < 28){
    float mean = lmean[x], inv = linv[x];
    int tok = 1 + (t*28 + y)*28 + x;
    short8 o;
    #pragma unroll
    for (int j = 0; j < 8; ++j)
      o[j] = (short)f2b((val[j] - mean)*inv*gls[dg*8+j] + bls[dg*8+j]);
    *(short8*)(qp + ((size_t)bh*6273 + tok)*96 + dg*8) = o;
  } else if (has_cls && tid >= 348 && tid < 360){
    int cdg = tid - 348;
    float mean = lmean[28], inv = linv[28];
    short8 o;
    #pragma unroll
    for (int j = 0; j < 8; ++j)
      o[j] = (short)f2b((val[j] - mean)*inv*gls[cdg*8+j] + bls[cdg*8+j]);
    *(short8*)(qp + (size_t)bh*6273*96 + cdg*8) = o;
  }
}

// ---------------- K3: k/v pooling (stride 1,8,8) + LN; v stored transposed ----------------
__global__ __launch_bounds__(128) void k_poolkv(
    const unsigned short* __restrict__ kr, const unsigned short* __restrict__ vr,
    const unsigned short* __restrict__ cwk, const unsigned short* __restrict__ gk, const unsigned short* __restrict__ bk,
    const unsigned short* __restrict__ cwv, const unsigned short* __restrict__ gv, const unsigned short* __restrict__ bv,
    unsigned short* __restrict__ kp, unsigned short* __restrict__ vt)
{
  const int bid = blockIdx.x;            // bh*416 + key
  const int isv = blockIdx.y;
  const int bh = bid / 416; const int key = bid - bh*416;
  const int d = threadIdx.x;
  if (key >= 393){
    if (d < 96){
      if (isv == 0) kp[((size_t)bh*416 + key)*96 + d] = 0;
      else          vt[((size_t)bh*96 + d)*416 + key] = 0;
    }
    return;
  }
  const unsigned short* raw = (isv == 0 ? kr : vr) + (size_t)bh*2408544;
  const unsigned short* cw = (isv == 0) ? cwk : cwv;
  const unsigned short* g  = (isv == 0) ? gk : gv;
  const unsigned short* bt = (isv == 0) ? bk : bv;
  float val = 0.f;
  if (d < 96){
    if (key == 0) val = b2f(raw[d]);
    else {
      int s = key - 1; int t = s / 49; int r2 = s - t*49; int y = r2 / 7; int xx = r2 - y*7;
      const unsigned short* wr = cw + d*27;
      float sum = 0.f;
      for (int dt = 0; dt < 3; ++dt){
        int tt = t + dt - 1; if (tt < 0 || tt >= 8) continue;
        for (int dy = 0; dy < 3; ++dy){
          int yy = 8*y + dy - 1; if (yy < 0 || yy >= 56) continue;
          for (int dx = 0; dx < 3; ++dx){
            int xv = 8*xx + dx - 1; if (xv < 0 || xv >= 56) continue;
            sum += b2f(raw[(size_t)(1 + (tt*56 + yy)*56 + xv)*96 + d]) * b2f(wr[(dt*3+dy)*3+dx]);
          }
        }
      }
      val = sum;
    }
  }
  __shared__ float r1[128], r2s[128];
  r1[threadIdx.x] = (d < 96) ? val : 0.f;
  r2s[threadIdx.x] = (d < 96) ? val*val : 0.f;
  __syncthreads();
  for (int off = 64; off > 0; off >>= 1){
    if ((int)threadIdx.x < off){ r1[threadIdx.x] += r1[threadIdx.x+off]; r2s[threadIdx.x] += r2s[threadIdx.x+off]; }
    __syncthreads();
  }
  if (d < 96){
    float mean = r1[0] * (1.f/96.f);
    float var  = r2s[0] * (1.f/96.f) - mean*mean;
    float inv = rsqrtf(var + 1e-5f);
    float o = (val - mean)*inv*b2f(g[d]) + b2f(bt[d]);
    if (isv == 0) kp[((size_t)bh*416 + key)*96 + d] = f2b(o);
    else          vt[((size_t)bh*96 + d)*416 + key] = f2b(o);
  }
}

// ---------------- K4: fused attention (16 queries / block, 6 waves) --------
// All independent global loads issued before first barrier. No register state
// held across the softmax barrier (r4's spill bug). P bf16 in-place over S.
#define SSTR 436
__global__ __launch_bounds__(384) void k_attn(
    const unsigned short* __restrict__ qp, const unsigned short* __restrict__ kp,
    const unsigned short* __restrict__ vt,
    const unsigned short* __restrict__ rph, const unsigned short* __restrict__ rpw,
    const unsigned short* __restrict__ rpt,
    unsigned short* __restrict__ ao)
{
  __shared__ __align__(16) unsigned short qs[16*104];
  __shared__ __align__(16) float S[16*SSTR];     // P (ushort, stride 872) aliases this
  __shared__ float dh[16][7], dw[16][7], dtb[16][8];
  __shared__ unsigned int coords[416];
  __shared__ float linv[16];

  const int qb = blockIdx.x;
  const int bh = blockIdx.y;
  const int bb = bh >> 1, head = bh & 1;
  const int q0 = qb * 16;
  const int tid = threadIdx.x;
  const int lane = tid & 63;
  const int wv = tid >> 6;

  const unsigned short* qbase = qp + (size_t)bh*6273*96;
  const unsigned short* kbase = kp + (size_t)bh*416*96;
  const unsigned short* vbase = vt + (size_t)bh*96*416;

  // ---- issue ALL independent global loads up front ----
  const int kq = (lane >> 4) * 8;

  // K tiles wv and wv+6 (always < 26 since wv<=5)
  short8 kb[2][3];
  {
    int key0 = wv*16 + (lane & 15);
    const unsigned short* kr0 = kbase + (size_t)key0*96 + kq;
    kb[0][0] = *(const short8*)(kr0); kb[0][1] = *(const short8*)(kr0+32); kb[0][2] = *(const short8*)(kr0+64);
    const unsigned short* kr1 = kr0 + 96*96;
    kb[1][0] = *(const short8*)(kr1); kb[1][1] = *(const short8*)(kr1+32); kb[1][2] = *(const short8*)(kr1+64);
  }
  // Q fragments straight from global (no LDS dependency)
  short8 a0, a1, a2;
  {
    int qa = q0 + (lane & 15); if (qa > 6272) qa = 6272;
    const unsigned short* qrow = qbase + (size_t)qa*96 + kq;
    a0 = *(const short8*)(qrow);
    a1 = *(const short8*)(qrow + 32);
    a2 = *(const short8*)(qrow + 64);
  }
  // stage Q tile to LDS (for rel-dots + residual)
  if (tid < 192){
    int m = tid / 12, c8 = (tid - m*12)*8;
    int gq = q0 + m; if (gq > 6272) gq = 6272;
    *(short8*)(qs + m*104 + c8) = *(const short8*)(qbase + (size_t)gq*96 + c8);
  }
  // key coord table
  for (int j = tid; j < 416; j += 384){
    unsigned int c;
    if (j == 0) c = 0u;                       // cls key: no rel
    else if (j >= 393) c = 2u << 24;          // pad
    else {
      int ks = j - 1; int kt = ks / 49; int krm = ks - kt*49; int ky = krm / 7; int kx = krm - ky*7;
      c = (unsigned)kt | ((unsigned)ky << 8) | ((unsigned)kx << 16) | (1u << 24);
    }
    coords[j] = c;
  }
  __syncthreads();

  // ---- rel-pos dot tables (K loads still in flight / L2-warm) ----
  if (tid < 352){
    int m = tid / 22, e = tid - m*22;
    int gq = q0 + m;
    float acc8[8] = {0,0,0,0,0,0,0,0};
    bool live = (gq >= 1 && gq <= 6272);
    if (live){
      int s = gq - 1; int t = s / 784; int r2 = s - t*784; int y = r2 / 28; int xx = r2 - y*28;
      const unsigned short* rrow;
      if (e < 7)       rrow = rph + (size_t)(y  - 4*e       + 24)*96;
      else if (e < 14) rrow = rpw + (size_t)(xx - 4*(e-7)   + 24)*96;
      else             rrow = rpt + (size_t)(t  -   (e-14)  + 7 )*96;
      #pragma unroll
      for (int c = 0; c < 12; ++c){
        short8 a = *(const short8*)(qs + m*104 + c*8);
        short8 r = *(const short8*)(rrow + c*8);
        #pragma unroll
        for (int j = 0; j < 8; ++j) acc8[j] += b2f((unsigned short)a[j]) * b2f((unsigned short)r[j]);
      }
    }
    float dot = ((acc8[0]+acc8[1])+(acc8[2]+acc8[3])) + ((acc8[4]+acc8[5])+(acc8[6]+acc8[7]));
    if (e < 7) dh[m][e] = dot; else if (e < 14) dw[m][e-7] = dot; else dtb[m][e-14] = dot;
  }

  // ---- QK^T tiles: compute tile it, prefetch tile it+2 ----
  const int nt = (25 - wv)/6 + 1;             // 5 for wv<2, else 4
  for (int it = 0; it < nt; ++it){
    int t16 = wv + 6*it;
    floatx4 acc = {0.f,0.f,0.f,0.f};
    acc = __builtin_amdgcn_mfma_f32_16x16x32_bf16(a0, kb[it&1][0], acc, 0,0,0);
    acc = __builtin_amdgcn_mfma_f32_16x16x32_bf16(a1, kb[it&1][1], acc, 0,0,0);
    acc = __builtin_amdgcn_mfma_f32_16x16x32_bf16(a2, kb[it&1][2], acc, 0,0,0);
    if (it + 2 < nt){
      int keyn = (wv + 6*(it+2))*16 + (lane & 15);
      const unsigned short* krn = kbase + (size_t)keyn*96 + kq;
      kb[it&1][0] = *(const short8*)(krn);
      kb[it&1][1] = *(const short8*)(krn+32);
      kb[it&1][2] = *(const short8*)(krn+64);
    }
    int key = t16*16 + (lane & 15);
    #pragma unroll
    for (int r = 0; r < 4; ++r){
      int m = (lane >> 4)*4 + r;
      S[m*SSTR + key] = acc[r] * SCALE_F;
    }
  }
  __syncthreads();

  // ---- softmax (rows in registers), P = bf16 exp (unnormalized) in-place ----
  if (tid < 256){
    const int m = tid >> 4, sub = tid & 15;
    const int gq = q0 + m;
    float sv[26];
    #pragma unroll
    for (int i = 0; i < 26; ++i){
      int j = sub + 16*i;
      float s = S[m*SSTR + j];
      unsigned int c = coords[j];
      unsigned int fl = c >> 24;
      if (fl == 2u) s = -1e30f;
      else if (fl == 1u && gq >= 1)
        s += dtb[m][c & 0xFF] + dh[m][(c >> 8) & 0xFF] + dw[m][(c >> 16) & 0xFF];
      sv[i] = s;
    }
    float mx = sv[0];
    #pragma unroll
    for (int i = 1; i < 26; ++i) mx = fmaxf(mx, sv[i]);
    #pragma unroll
    for (int o = 1; o < 16; o <<= 1) mx = fmaxf(mx, __shfl_xor(mx, o, 64));
    float sum = 0.f;
    #pragma unroll
    for (int i = 0; i < 26; ++i){ sv[i] = __expf(sv[i] - mx); sum += sv[i]; }
    #pragma unroll
    for (int o = 1; o < 16; o <<= 1) sum += __shfl_xor(sum, o, 64);
    if (sub == 0) linv[m] = 1.f / sum;
    unsigned short* P = (unsigned short*)S;
    #pragma unroll
    for (int i = 0; i < 26; ++i) P[m*872 + sub + 16*i] = f2b(sv[i]);
  }
  __syncthreads();

  // ---- PV (V loaded now, not held across barrier) + residual, scaled by 1/sum ----
  {
    const int dd = wv*16 + (lane & 15);
    const unsigned short* vrow = vbase + (size_t)dd*416 + kq;
    const unsigned short* P = (const unsigned short*)S;
    const unsigned short* prow = P + (lane & 15)*872 + kq;
    floatx4 acc = {0.f,0.f,0.f,0.f};
    #pragma unroll
    for (int s = 0; s < 13; ++s){
      short8 pa = *(const short8*)(prow + 32*s);
      short8 vb = *(const short8*)(vrow + 32*s);
      acc = __builtin_amdgcn_mfma_f32_16x16x32_bf16(pa, vb, acc, 0,0,0);
    }
    #pragma unroll
    for (int r = 0; r < 4; ++r){
      int m = (lane >> 4)*4 + r;
      int gq = q0 + m;
      if (gq <= 6272){
        float o = acc[r] * linv[m] + b2f(qs[m*104 + dd]);
        ao[((size_t)bb*6273 + gq)*192 + head*96 + dd] = f2b(o);
      }
    }
  }
}

// ---------------- K5: proj GEMM (flag-aware output dtype) ----------------
__global__ __launch_bounds__(256) void k_proj(
    const unsigned short* __restrict__ ao, const unsigned short* __restrict__ w,
    const unsigned short* __restrict__ bias, void* __restrict__ out, const int* __restrict__ flagp)
{
  const int flag = *flagp;
  const int lane = threadIdx.x & 63;
  const int wv = threadIdx.x >> 6;
  const int c = blockIdx.y*64 + wv*16 + (lane & 15);
  const int kq = (lane >> 4) * 8;
  short8 bfr[6];
  const unsigned short* wrow = w + c*192 + kq;
  #pragma unroll
  for (int s = 0; s < 6; ++s) bfr[s] = *(const short8*)(wrow + 32*s);
  float bv = b2f(bias[c]);
  const int m_base = blockIdx.x * 64;
  for (int i = 0; i < 4; ++i){
    int mt = m_base + i*16;
    int ma = mt + (lane & 15); if (ma > 25091) ma = 25091;
    const unsigned short* arow = ao + (size_t)ma*192 + kq;
    floatx4 acc = {0.f,0.f,0.f,0.f};
    #pragma unroll
    for (int s = 0; s < 6; ++s){
      short8 a = *(const short8*)(arow + 32*s);
      acc = __builtin_amdgcn_mfma_f32_16x16x32_bf16(a, bfr[s], acc, 0,0,0);
    }
    #pragma unroll
    for (int r = 0; r < 4; ++r){
      int m = mt + (lane >> 4)*4 + r;
      if (m < 25092){
        float o = acc[r] + bv;
        if (flag) ((float*)out)[(size_t)m*192 + c] = o;
        else      ((unsigned short*)out)[(size_t)m*192 + c] = f2b(o);
      }
    }
  }
}

extern "C" void kernel_launch(void* const* d_in, const int* in_sizes, int n_in,
                              void* d_out, int out_size, void* d_ws, size_t ws_size,
                              hipStream_t stream)
{
  char* p = (char*)d_ws;
  int* flagp = (int*)p; p += 16;
  unsigned short* conv = (unsigned short*)p;

  ConvDesc desc;
  long long cum = 0;
  for (int i = 0; i < 17; ++i){
    desc.src[i] = d_in[i];
    desc.off[i] = cum;
    desc.count[i] = in_sizes[i];
    cum += in_sizes[i];
  }
  p += (size_t)cum * 2;

  unsigned short* q_raw  = (unsigned short*)p; p += (size_t)19268352*2;
  unsigned short* k_raw  = (unsigned short*)p; p += (size_t)19268352*2;
  unsigned short* v_raw  = (unsigned short*)p; p += (size_t)19268352*2;
  unsigned short* q_pool = (unsigned short*)p; p += (size_t)4817664*2;
  unsigned short* k_pool = (unsigned short*)p; p += (size_t)319488*2;
  unsigned short* v_t    = (unsigned short*)p; p += (size_t)319488*2;
  unsigned short* a_out  = q_raw;   // q_raw dead after k_poolq

  const unsigned short* cx     = conv + desc.off[0];
  const unsigned short* cqkv_w = conv + desc.off[1];
  const unsigned short* cqkv_b = conv + desc.off[2];
  const unsigned short* cproj_w= conv + desc.off[3];
  const unsigned short* cproj_b= conv + desc.off[4];
  const unsigned short* cpq_w  = conv + desc.off[5];
  const unsigned short* cnq_g  = conv + desc.off[6];
  const unsigned short* cnq_b  = conv + desc.off[7];
  const unsigned short* cpk_w  = conv + desc.off[8];
  const unsigned short* cnk_g  = conv + desc.off[9];
  const unsigned short* cnk_b  = conv + desc.off[10];
  const unsigned short* cpv_w  = conv + desc.off[11];
  const unsigned short* cnv_g  = conv + desc.off[12];
  const unsigned short* cnv_b  = conv + desc.off[13];
  const unsigned short* crph   = conv + desc.off[14];
  const unsigned short* crpw   = conv + desc.off[15];
  const unsigned short* crpt   = conv + desc.off[16];

  k_convert<<<dim3(592, 17), 256, 0, stream>>>(desc, conv, flagp, (const unsigned int*)d_in[0]);
  k_qkv  <<<dim3(1569), 256, 0, stream>>>(cx, cqkv_w, cqkv_b, q_raw, k_raw, v_raw);
  k_poolq<<<dim3(28, 8, 8), 384, 0, stream>>>(q_raw, cpq_w, cnq_g, cnq_b, q_pool);
  k_poolkv<<<dim3(8*416, 2), 128, 0, stream>>>(k_raw, v_raw, cpk_w, cnk_g, cnk_b, cpv_w, cnv_g, cnv_b, k_pool, v_t);
  k_attn <<<dim3(393, 8), 384, 0, stream>>>(q_pool, k_pool, v_t, crph, crpw, crpt, a_out);
  k_proj <<<dim3(393, 3), 256, 0, stream>>>(a_out, cproj_w, cproj_b, d_out, flagp);
}

// Round 6
// 396.584 us; speedup vs baseline: 3.7786x; 3.7786x over previous
//
#include <hip/hip_runtime.h>
#include <hip/hip_bf16.h>

typedef short short8 __attribute__((ext_vector_type(8)));
typedef float floatx4 __attribute__((ext_vector_type(4)));

#define SCALE_F 0.10206207261596575f

static __device__ __forceinline__ float b2f(unsigned short u){
  unsigned int v = ((unsigned int)u) << 16; float f;
  __builtin_memcpy(&f, &v, 4); return f;
}
static __device__ __forceinline__ unsigned short f2b(float f){
  __hip_bfloat16 h = __float2bfloat16(f);
  unsigned short u; __builtin_memcpy(&u, &h, 2); return u;
}

struct ConvDesc {
  const void* src[17];
  long long off[17];
  int count[17];
};

// ---------------- K0: dtype detect + convert all float tensors to bf16 ----------------
__global__ __launch_bounds__(256) void k_convert(ConvDesc d, unsigned short* dst_base,
                                                 int* flagp, const unsigned int* xprobe)
{
  __shared__ int sflag;
  if (threadIdx.x < 64){
    unsigned int w = xprobe[1024 + threadIdx.x];
    int e = (w >> 7) & 0xFF;           // exponent of LOW ushort viewed as bf16
    int pl = (e >= 90 && e <= 140) ? 1 : 0;
    unsigned long long m = __ballot(pl);
    if (threadIdx.x == 0){
      sflag = (__popcll(m) < 40) ? 1 : 0;   // 1 = inputs are fp32
      if (blockIdx.x == 0 && blockIdx.y == 0) *flagp = sflag;
    }
  }
  __syncthreads();
  const int flag = sflag;
  const int t = blockIdx.y;
  const int cnt = d.count[t];
  unsigned short* dst = dst_base + d.off[t];
  const float* sf = (const float*)d.src[t];
  const unsigned short* su = (const unsigned short*)d.src[t];
  for (int i = blockIdx.x*blockDim.x + threadIdx.x; i < cnt; i += gridDim.x*blockDim.x){
    dst[i] = flag ? f2b(sf[i]) : su[i];
  }
}

// ---------------- K1: QKV GEMM (x read once per row-tile; all 576 cols per block) ------
__global__ __launch_bounds__(256) void k_qkv(
    const unsigned short* __restrict__ x, const unsigned short* __restrict__ w,
    const unsigned short* __restrict__ bias,
    unsigned short* __restrict__ qr, unsigned short* __restrict__ kr, unsigned short* __restrict__ vr)
{
  const int lane = threadIdx.x & 63;
  const int wv = threadIdx.x >> 6;
  const int kq = (lane >> 4) * 8;
  const int m_base = blockIdx.x * 64 + wv * 16;   // this wave's 16 rows

  int ma = m_base + (lane & 15); if (ma > 100355) ma = 100355;
  const unsigned short* xrow = x + (size_t)ma*96 + kq;
  short8 a0 = *(const short8*)(xrow);
  short8 a1 = *(const short8*)(xrow + 32);
  short8 a2 = *(const short8*)(xrow + 64);

  size_t base0[4];
  int mrow[4];
  #pragma unroll
  for (int r = 0; r < 4; ++r){
    int m = m_base + (lane >> 4)*4 + r;
    mrow[r] = m;
    int bb = m / 25089; int n = m - bb*25089;
    base0[r] = ((size_t)(bb*2)*25089 + n)*96;
  }

  for (int ct = 0; ct < 36; ++ct){
    int col = ct*16 + (lane & 15);
    const unsigned short* wrow = w + col*96 + kq;
    short8 b0 = *(const short8*)(wrow);
    short8 b1 = *(const short8*)(wrow + 32);
    short8 b2 = *(const short8*)(wrow + 64);
    float bv = b2f(bias[col]);
    floatx4 acc = {0.f,0.f,0.f,0.f};
    acc = __builtin_amdgcn_mfma_f32_16x16x32_bf16(a0, b0, acc, 0,0,0);
    acc = __builtin_amdgcn_mfma_f32_16x16x32_bf16(a1, b1, acc, 0,0,0);
    acc = __builtin_amdgcn_mfma_f32_16x16x32_bf16(a2, b2, acc, 0,0,0);
    int which = col / 192; int rem = col - which*192; int head = rem / 96; int d = rem - head*96;
    unsigned short* ob = (which == 0) ? qr : ((which == 1) ? kr : vr);
    size_t hoff = (size_t)head * 2408544 + d;
    #pragma unroll
    for (int r = 0; r < 4; ++r){
      if (mrow[r] < 100356) ob[base0[r] + hoff] = f2b(acc[r] + bv);
    }
  }
}

// ---------------- K2: q pooling (stride 1,2,2) + LN — tile-based, vectorized ----------
__global__ __launch_bounds__(384) void k_poolq(
    const unsigned short* __restrict__ qr, const unsigned short* __restrict__ cw,
    const unsigned short* __restrict__ g, const unsigned short* __restrict__ bta,
    unsigned short* __restrict__ qp)
{
  __shared__ float wlds[27*96];
  __shared__ float gls[96], bls[96];
  __shared__ float ls1[29*12], ls2[29*12];
  __shared__ float lmean[29], linv[29];

  const int y  = blockIdx.x;
  const int t  = blockIdx.y;
  const int bh = blockIdx.z;
  const int tid = threadIdx.x;
  const bool has_cls = (y == 0 && t == 0);
  const unsigned short* base = qr + (size_t)bh*2408544;

  for (int idx = tid; idx < 27*96; idx += 384){
    int tap = idx / 96, d = idx - tap*96;
    wlds[idx] = b2f(cw[d*27 + tap]);
  }
  for (int idx = tid; idx < 96; idx += 384){
    gls[idx] = b2f(g[idx]); bls[idx] = b2f(bta[idx]);
  }
  __syncthreads();

  const int x = tid / 12, dg = tid - x*12;
  float val[8] = {0,0,0,0,0,0,0,0};

  if (x < 28){
    #pragma unroll
    for (int dt = 0; dt < 3; ++dt){
      int tt = t + dt - 1; if (tt < 0 || tt >= 8) continue;
      #pragma unroll
      for (int dy = 0; dy < 3; ++dy){
        int yy = 2*y + dy - 1; if (yy < 0 || yy >= 56) continue;
        #pragma unroll
        for (int dx = 0; dx < 3; ++dx){
          int xv = 2*x + dx - 1; if (xv < 0 || xv >= 56) continue;
          const int tap = (dt*3+dy)*3+dx;
          short8 v = *(const short8*)(base + (size_t)(1 + (tt*56 + yy)*56 + xv)*96 + dg*8);
          const float* wr = wlds + tap*96 + dg*8;
          #pragma unroll
          for (int j = 0; j < 8; ++j) val[j] += b2f((unsigned short)v[j]) * wr[j];
        }
      }
    }
    float s1 = 0.f, s2 = 0.f;
    #pragma unroll
    for (int j = 0; j < 8; ++j){ s1 += val[j]; s2 += val[j]*val[j]; }
    ls1[x*12+dg] = s1; ls2[x*12+dg] = s2;
  } else if (has_cls && tid >= 348 && tid < 360){
    int cdg = tid - 348;
    short8 v = *(const short8*)(base + cdg*8);
    float s1 = 0.f, s2 = 0.f;
    #pragma unroll
    for (int j = 0; j < 8; ++j){ val[j] = b2f((unsigned short)v[j]); s1 += val[j]; s2 += val[j]*val[j]; }
    ls1[28*12+cdg] = s1; ls2[28*12+cdg] = s2;
  }
  __syncthreads();

  if (tid < 28 || (tid == 28 && has_cls)){
    float s1 = 0.f, s2 = 0.f;
    #pragma unroll
    for (int k = 0; k < 12; ++k){ s1 += ls1[tid*12+k]; s2 += ls2[tid*12+k]; }
    float mean = s1 * (1.f/96.f);
    float var  = s2 * (1.f/96.f) - mean*mean;
    lmean[tid] = mean; linv[tid] = rsqrtf(var + 1e-5f);
  }
  __syncthreads();

  if (x < 28){
    float mean = lmean[x], inv = linv[x];
    int tok = 1 + (t*28 + y)*28 + x;
    short8 o;
    #pragma unroll
    for (int j = 0; j < 8; ++j)
      o[j] = (short)f2b((val[j] - mean)*inv*gls[dg*8+j] + bls[dg*8+j]);
    *(short8*)(qp + ((size_t)bh*6273 + tok)*96 + dg*8) = o;
  } else if (has_cls && tid >= 348 && tid < 360){
    int cdg = tid - 348;
    float mean = lmean[28], inv = linv[28];
    short8 o;
    #pragma unroll
    for (int j = 0; j < 8; ++j)
      o[j] = (short)f2b((val[j] - mean)*inv*gls[cdg*8+j] + bls[cdg*8+j]);
    *(short8*)(qp + (size_t)bh*6273*96 + cdg*8) = o;
  }
}

// ---------------- K3: k/v pooling (stride 1,8,8) + LN; v stored transposed ----------------
__global__ __launch_bounds__(128) void k_poolkv(
    const unsigned short* __restrict__ kr, const unsigned short* __restrict__ vr,
    const unsigned short* __restrict__ cwk, const unsigned short* __restrict__ gk, const unsigned short* __restrict__ bk,
    const unsigned short* __restrict__ cwv, const unsigned short* __restrict__ gv, const unsigned short* __restrict__ bv,
    unsigned short* __restrict__ kp, unsigned short* __restrict__ vt)
{
  const int bid = blockIdx.x;            // bh*416 + key
  const int isv = blockIdx.y;
  const int bh = bid / 416; const int key = bid - bh*416;
  const int d = threadIdx.x;
  if (key >= 393){
    if (d < 96){
      if (isv == 0) kp[((size_t)bh*416 + key)*96 + d] = 0;
      else          vt[((size_t)bh*96 + d)*416 + key] = 0;
    }
    return;
  }
  const unsigned short* raw = (isv == 0 ? kr : vr) + (size_t)bh*2408544;
  const unsigned short* cw = (isv == 0) ? cwk : cwv;
  const unsigned short* g  = (isv == 0) ? gk : gv;
  const unsigned short* bt = (isv == 0) ? bk : bv;
  float val = 0.f;
  if (d < 96){
    if (key == 0) val = b2f(raw[d]);
    else {
      int s = key - 1; int t = s / 49; int r2 = s - t*49; int y = r2 / 7; int xx = r2 - y*7;
      const unsigned short* wr = cw + d*27;
      float sum = 0.f;
      for (int dt = 0; dt < 3; ++dt){
        int tt = t + dt - 1; if (tt < 0 || tt >= 8) continue;
        for (int dy = 0; dy < 3; ++dy){
          int yy = 8*y + dy - 1; if (yy < 0 || yy >= 56) continue;
          for (int dx = 0; dx < 3; ++dx){
            int xv = 8*xx + dx - 1; if (xv < 0 || xv >= 56) continue;
            sum += b2f(raw[(size_t)(1 + (tt*56 + yy)*56 + xv)*96 + d]) * b2f(wr[(dt*3+dy)*3+dx]);
          }
        }
      }
      val = sum;
    }
  }
  __shared__ float r1[128], r2s[128];
  r1[threadIdx.x] = (d < 96) ? val : 0.f;
  r2s[threadIdx.x] = (d < 96) ? val*val : 0.f;
  __syncthreads();
  for (int off = 64; off > 0; off >>= 1){
    if ((int)threadIdx.x < off){ r1[threadIdx.x] += r1[threadIdx.x+off]; r2s[threadIdx.x] += r2s[threadIdx.x+off]; }
    __syncthreads();
  }
  if (d < 96){
    float mean = r1[0] * (1.f/96.f);
    float var  = r2s[0] * (1.f/96.f) - mean*mean;
    float inv = rsqrtf(var + 1e-5f);
    float o = (val - mean)*inv*b2f(g[d]) + b2f(bt[d]);
    if (isv == 0) kp[((size_t)bh*416 + key)*96 + d] = f2b(o);
    else          vt[((size_t)bh*96 + d)*416 + key] = f2b(o);
  }
}

// ---------------- K4: fused attention (16 queries / block, 6 waves) --------
// QK^T K-loop is a compile-time unrolled 5-step with explicit register
// rotation — NO dynamically-indexed register arrays (r4/r5's scratch bug).
#define SSTR 436
__global__ __launch_bounds__(384) void k_attn(
    const unsigned short* __restrict__ qp, const unsigned short* __restrict__ kp,
    const unsigned short* __restrict__ vt,
    const unsigned short* __restrict__ rph, const unsigned short* __restrict__ rpw,
    const unsigned short* __restrict__ rpt,
    unsigned short* __restrict__ ao)
{
  __shared__ __align__(16) unsigned short qs[16*104];
  __shared__ __align__(16) float S[16*SSTR];     // P (ushort, stride 872) aliases this
  __shared__ float dh[16][7], dw[16][7], dtb[16][8];
  __shared__ unsigned int coords[416];
  __shared__ float linv[16];

  const int qb = blockIdx.x;
  const int bh = blockIdx.y;
  const int bb = bh >> 1, head = bh & 1;
  const int q0 = qb * 16;
  const int tid = threadIdx.x;
  const int lane = tid & 63;
  const int wv = tid >> 6;

  const unsigned short* qbase = qp + (size_t)bh*6273*96;
  const unsigned short* kbase = kp + (size_t)bh*416*96;
  const unsigned short* vbase = vt + (size_t)bh*96*416;

  const int kq = (lane >> 4) * 8;
  const int key_l = lane & 15;

  // ---- upfront loads: K tiles wv, wv+6 (static registers) ----
  short8 c0, c1, c2, n0, n1, n2;
  {
    const unsigned short* kr0 = kbase + (size_t)(wv*16 + key_l)*96 + kq;
    c0 = *(const short8*)(kr0); c1 = *(const short8*)(kr0+32); c2 = *(const short8*)(kr0+64);
    const unsigned short* kr1 = kr0 + 96*96;
    n0 = *(const short8*)(kr1); n1 = *(const short8*)(kr1+32); n2 = *(const short8*)(kr1+64);
  }
  // Q fragments straight from global
  short8 a0, a1, a2;
  {
    int qa = q0 + key_l; if (qa > 6272) qa = 6272;
    const unsigned short* qrow = qbase + (size_t)qa*96 + kq;
    a0 = *(const short8*)(qrow);
    a1 = *(const short8*)(qrow + 32);
    a2 = *(const short8*)(qrow + 64);
  }
  // stage Q tile to LDS (for rel-dots + residual)
  if (tid < 192){
    int m = tid / 12, c8 = (tid - m*12)*8;
    int gq = q0 + m; if (gq > 6272) gq = 6272;
    *(short8*)(qs + m*104 + c8) = *(const short8*)(qbase + (size_t)gq*96 + c8);
  }
  // key coord table
  for (int j = tid; j < 416; j += 384){
    unsigned int c;
    if (j == 0) c = 0u;                       // cls key: no rel
    else if (j >= 393) c = 2u << 24;          // pad
    else {
      int ks = j - 1; int kt = ks / 49; int krm = ks - kt*49; int ky = krm / 7; int kx = krm - ky*7;
      c = (unsigned)kt | ((unsigned)ky << 8) | ((unsigned)kx << 16) | (1u << 24);
    }
    coords[j] = c;
  }
  __syncthreads();

  // ---- rel-pos dot tables (K loads in flight) ----
  if (tid < 352){
    int m = tid / 22, e = tid - m*22;
    int gq = q0 + m;
    float acc8[8] = {0,0,0,0,0,0,0,0};
    bool live = (gq >= 1 && gq <= 6272);
    if (live){
      int s = gq - 1; int t = s / 784; int r2 = s - t*784; int y = r2 / 28; int xx = r2 - y*28;
      const unsigned short* rrow;
      if (e < 7)       rrow = rph + (size_t)(y  - 4*e       + 24)*96;
      else if (e < 14) rrow = rpw + (size_t)(xx - 4*(e-7)   + 24)*96;
      else             rrow = rpt + (size_t)(t  -   (e-14)  + 7 )*96;
      #pragma unroll
      for (int c = 0; c < 12; ++c){
        short8 a = *(const short8*)(qs + m*104 + c*8);
        short8 r = *(const short8*)(rrow + c*8);
        #pragma unroll
        for (int j = 0; j < 8; ++j) acc8[j] += b2f((unsigned short)a[j]) * b2f((unsigned short)r[j]);
      }
    }
    float dot = ((acc8[0]+acc8[1])+(acc8[2]+acc8[3])) + ((acc8[4]+acc8[5])+(acc8[6]+acc8[7]));
    if (e < 7) dh[m][e] = dot; else if (e < 14) dw[m][e-7] = dot; else dtb[m][e-14] = dot;
  }

  // ---- QK^T: 5 static iterations, register rotation, guards for dead tiles ----
  #pragma unroll
  for (int it = 0; it < 5; ++it){
    const int t16 = wv + 6*it;
    if (t16 < 26){
      floatx4 acc = {0.f,0.f,0.f,0.f};
      acc = __builtin_amdgcn_mfma_f32_16x16x32_bf16(a0, c0, acc, 0,0,0);
      acc = __builtin_amdgcn_mfma_f32_16x16x32_bf16(a1, c1, acc, 0,0,0);
      acc = __builtin_amdgcn_mfma_f32_16x16x32_bf16(a2, c2, acc, 0,0,0);
      int key = t16*16 + key_l;
      #pragma unroll
      for (int r = 0; r < 4; ++r){
        int m = (lane >> 4)*4 + r;
        S[m*SSTR + key] = acc[r] * SCALE_F;
      }
    }
    // rotate and prefetch tile wv + 6*(it+2)
    c0 = n0; c1 = n1; c2 = n2;
    const int t16n = wv + 6*(it + 2);
    if (t16n < 26){
      const unsigned short* krn = kbase + (size_t)(t16n*16 + key_l)*96 + kq;
      n0 = *(const short8*)(krn);
      n1 = *(const short8*)(krn + 32);
      n2 = *(const short8*)(krn + 64);
    }
  }
  __syncthreads();

  // ---- softmax (rows in registers), P = bf16 exp (unnormalized) in-place ----
  if (tid < 256){
    const int m = tid >> 4, sub = tid & 15;
    const int gq = q0 + m;
    float sv[26];
    #pragma unroll
    for (int i = 0; i < 26; ++i){
      int j = sub + 16*i;
      float s = S[m*SSTR + j];
      unsigned int c = coords[j];
      unsigned int fl = c >> 24;
      if (fl == 2u) s = -1e30f;
      else if (fl == 1u && gq >= 1)
        s += dtb[m][c & 0xFF] + dh[m][(c >> 8) & 0xFF] + dw[m][(c >> 16) & 0xFF];
      sv[i] = s;
    }
    float mx = sv[0];
    #pragma unroll
    for (int i = 1; i < 26; ++i) mx = fmaxf(mx, sv[i]);
    #pragma unroll
    for (int o = 1; o < 16; o <<= 1) mx = fmaxf(mx, __shfl_xor(mx, o, 64));
    float sum = 0.f;
    #pragma unroll
    for (int i = 0; i < 26; ++i){ sv[i] = __expf(sv[i] - mx); sum += sv[i]; }
    #pragma unroll
    for (int o = 1; o < 16; o <<= 1) sum += __shfl_xor(sum, o, 64);
    if (sub == 0) linv[m] = 1.f / sum;
    unsigned short* P = (unsigned short*)S;
    #pragma unroll
    for (int i = 0; i < 26; ++i) P[m*872 + sub + 16*i] = f2b(sv[i]);
  }
  __syncthreads();

  // ---- PV + residual, scaled by 1/sum ----
  {
    const int dd = wv*16 + key_l;
    const unsigned short* vrow = vbase + (size_t)dd*416 + kq;
    const unsigned short* P = (const unsigned short*)S;
    const unsigned short* prow = P + key_l*872 + kq;
    floatx4 acc = {0.f,0.f,0.f,0.f};
    #pragma unroll
    for (int s = 0; s < 13; ++s){
      short8 pa = *(const short8*)(prow + 32*s);
      short8 vb = *(const short8*)(vrow + 32*s);
      acc = __builtin_amdgcn_mfma_f32_16x16x32_bf16(pa, vb, acc, 0,0,0);
    }
    #pragma unroll
    for (int r = 0; r < 4; ++r){
      int m = (lane >> 4)*4 + r;
      int gq = q0 + m;
      if (gq <= 6272){
        float o = acc[r] * linv[m] + b2f(qs[m*104 + dd]);
        ao[((size_t)bb*6273 + gq)*192 + head*96 + dd] = f2b(o);
      }
    }
  }
}

// ---------------- K5: proj GEMM (flag-aware output dtype) ----------------
__global__ __launch_bounds__(256) void k_proj(
    const unsigned short* __restrict__ ao, const unsigned short* __restrict__ w,
    const unsigned short* __restrict__ bias, void* __restrict__ out, const int* __restrict__ flagp)
{
  const int flag = *flagp;
  const int lane = threadIdx.x & 63;
  const int wv = threadIdx.x >> 6;
  const int c = blockIdx.y*64 + wv*16 + (lane & 15);
  const int kq = (lane >> 4) * 8;
  short8 bfr[6];
  const unsigned short* wrow = w + c*192 + kq;
  #pragma unroll
  for (int s = 0; s < 6; ++s) bfr[s] = *(const short8*)(wrow + 32*s);
  float bv = b2f(bias[c]);
  const int m_base = blockIdx.x * 64;
  for (int i = 0; i < 4; ++i){
    int mt = m_base + i*16;
    int ma = mt + (lane & 15); if (ma > 25091) ma = 25091;
    const unsigned short* arow = ao + (size_t)ma*192 + kq;
    floatx4 acc = {0.f,0.f,0.f,0.f};
    #pragma unroll
    for (int s = 0; s < 6; ++s){
      short8 a = *(const short8*)(arow + 32*s);
      acc = __builtin_amdgcn_mfma_f32_16x16x32_bf16(a, bfr[s], acc, 0,0,0);
    }
    #pragma unroll
    for (int r = 0; r < 4; ++r){
      int m = mt + (lane >> 4)*4 + r;
      if (m < 25092){
        float o = acc[r] + bv;
        if (flag) ((float*)out)[(size_t)m*192 + c] = o;
        else      ((unsigned short*)out)[(size_t)m*192 + c] = f2b(o);
      }
    }
  }
}

extern "C" void kernel_launch(void* const* d_in, const int* in_sizes, int n_in,
                              void* d_out, int out_size, void* d_ws, size_t ws_size,
                              hipStream_t stream)
{
  char* p = (char*)d_ws;
  int* flagp = (int*)p; p += 16;
  unsigned short* conv = (unsigned short*)p;

  ConvDesc desc;
  long long cum = 0;
  for (int i = 0; i < 17; ++i){
    desc.src[i] = d_in[i];
    desc.off[i] = cum;
    desc.count[i] = in_sizes[i];
    cum += in_sizes[i];
  }
  p += (size_t)cum * 2;

  unsigned short* q_raw  = (unsigned short*)p; p += (size_t)19268352*2;
  unsigned short* k_raw  = (unsigned short*)p; p += (size_t)19268352*2;
  unsigned short* v_raw  = (unsigned short*)p; p += (size_t)19268352*2;
  unsigned short* q_pool = (unsigned short*)p; p += (size_t)4817664*2;
  unsigned short* k_pool = (unsigned short*)p; p += (size_t)319488*2;
  unsigned short* v_t    = (unsigned short*)p; p += (size_t)319488*2;
  unsigned short* a_out  = q_raw;   // q_raw dead after k_poolq

  const unsigned short* cx     = conv + desc.off[0];
  const unsigned short* cqkv_w = conv + desc.off[1];
  const unsigned short* cqkv_b = conv + desc.off[2];
  const unsigned short* cproj_w= conv + desc.off[3];
  const unsigned short* cproj_b= conv + desc.off[4];
  const unsigned short* cpq_w  = conv + desc.off[5];
  const unsigned short* cnq_g  = conv + desc.off[6];
  const unsigned short* cnq_b  = conv + desc.off[7];
  const unsigned short* cpk_w  = conv + desc.off[8];
  const unsigned short* cnk_g  = conv + desc.off[9];
  const unsigned short* cnk_b  = conv + desc.off[10];
  const unsigned short* cpv_w  = conv + desc.off[11];
  const unsigned short* cnv_g  = conv + desc.off[12];
  const unsigned short* cnv_b  = conv + desc.off[13];
  const unsigned short* crph   = conv + desc.off[14];
  const unsigned short* crpw   = conv + desc.off[15];
  const unsigned short* crpt   = conv + desc.off[16];

  k_convert<<<dim3(592, 17), 256, 0, stream>>>(desc, conv, flagp, (const unsigned int*)d_in[0]);
  k_qkv  <<<dim3(1569), 256, 0, stream>>>(cx, cqkv_w, cqkv_b, q_raw, k_raw, v_raw);
  k_poolq<<<dim3(28, 8, 8), 384, 0, stream>>>(q_raw, cpq_w, cnq_g, cnq_b, q_pool);
  k_poolkv<<<dim3(8*416, 2), 128, 0, stream>>>(k_raw, v_raw, cpk_w, cnk_g, cnk_b, cpv_w, cnv_g, cnv_b, k_pool, v_t);
  k_attn <<<dim3(393, 8), 384, 0, stream>>>(q_pool, k_pool, v_t, crph, crpw, crpt, a_out);
  k_proj <<<dim3(393, 3), 256, 0, stream>>>(a_out, cproj_w, cproj_b, d_out, flagp);
}

// Round 7
// 359.245 us; speedup vs baseline: 4.1713x; 1.1039x over previous
//
#include <hip/hip_runtime.h>
#include <hip/hip_bf16.h>

typedef short short8 __attribute__((ext_vector_type(8)));
typedef float floatx4 __attribute__((ext_vector_type(4)));

#define SCALE_F 0.10206207261596575f

static __device__ __forceinline__ float b2f(unsigned short u){
  unsigned int v = ((unsigned int)u) << 16; float f;
  __builtin_memcpy(&f, &v, 4); return f;
}
static __device__ __forceinline__ unsigned short f2b(float f){
  __hip_bfloat16 h = __float2bfloat16(f);
  unsigned short u; __builtin_memcpy(&u, &h, 2); return u;
}

struct ConvDesc {
  const void* src[17];
  long long off[17];
  int count[17];
};

// ---------------- K0: dtype detect + convert all float tensors to bf16 ----------------
__global__ __launch_bounds__(256) void k_convert(ConvDesc d, unsigned short* dst_base,
                                                 int* flagp, const unsigned int* xprobe)
{
  __shared__ int sflag;
  if (threadIdx.x < 64){
    unsigned int w = xprobe[1024 + threadIdx.x];
    int e = (w >> 7) & 0xFF;
    int pl = (e >= 90 && e <= 140) ? 1 : 0;
    unsigned long long m = __ballot(pl);
    if (threadIdx.x == 0){
      sflag = (__popcll(m) < 40) ? 1 : 0;   // 1 = inputs are fp32
      if (blockIdx.x == 0 && blockIdx.y == 0) *flagp = sflag;
    }
  }
  __syncthreads();
  const int flag = sflag;
  const int t = blockIdx.y;
  const int cnt = d.count[t];
  unsigned short* dst = dst_base + d.off[t];
  const float* sf = (const float*)d.src[t];
  const unsigned short* su = (const unsigned short*)d.src[t];
  for (int i = blockIdx.x*blockDim.x + threadIdx.x; i < cnt; i += gridDim.x*blockDim.x){
    dst[i] = flag ? f2b(sf[i]) : su[i];
  }
}

// ---------------- K1: QKV GEMM ----------------
__global__ __launch_bounds__(256) void k_qkv(
    const unsigned short* __restrict__ x, const unsigned short* __restrict__ w,
    const unsigned short* __restrict__ bias,
    unsigned short* __restrict__ qr, unsigned short* __restrict__ kr, unsigned short* __restrict__ vr)
{
  const int lane = threadIdx.x & 63;
  const int wv = threadIdx.x >> 6;
  const int kq = (lane >> 4) * 8;
  const int m_base = blockIdx.x * 64 + wv * 16;

  int ma = m_base + (lane & 15); if (ma > 100355) ma = 100355;
  const unsigned short* xrow = x + (size_t)ma*96 + kq;
  short8 a0 = *(const short8*)(xrow);
  short8 a1 = *(const short8*)(xrow + 32);
  short8 a2 = *(const short8*)(xrow + 64);

  size_t base0[4];
  int mrow[4];
  #pragma unroll
  for (int r = 0; r < 4; ++r){
    int m = m_base + (lane >> 4)*4 + r;
    mrow[r] = m;
    int bb = m / 25089; int n = m - bb*25089;
    base0[r] = ((size_t)(bb*2)*25089 + n)*96;
  }

  for (int ct = 0; ct < 36; ++ct){
    int col = ct*16 + (lane & 15);
    const unsigned short* wrow = w + col*96 + kq;
    short8 b0 = *(const short8*)(wrow);
    short8 b1 = *(const short8*)(wrow + 32);
    short8 b2 = *(const short8*)(wrow + 64);
    float bv = b2f(bias[col]);
    floatx4 acc = {0.f,0.f,0.f,0.f};
    acc = __builtin_amdgcn_mfma_f32_16x16x32_bf16(a0, b0, acc, 0,0,0);
    acc = __builtin_amdgcn_mfma_f32_16x16x32_bf16(a1, b1, acc, 0,0,0);
    acc = __builtin_amdgcn_mfma_f32_16x16x32_bf16(a2, b2, acc, 0,0,0);
    int which = col / 192; int rem = col - which*192; int head = rem / 96; int d = rem - head*96;
    unsigned short* ob = (which == 0) ? qr : ((which == 1) ? kr : vr);
    size_t hoff = (size_t)head * 2408544 + d;
    #pragma unroll
    for (int r = 0; r < 4; ++r){
      if (mrow[r] < 100356) ob[base0[r] + hoff] = f2b(acc[r] + bv);
    }
  }
}

// ---------------- K2: q pooling (stride 1,2,2) + LN ----------
__global__ __launch_bounds__(384) void k_poolq(
    const unsigned short* __restrict__ qr, const unsigned short* __restrict__ cw,
    const unsigned short* __restrict__ g, const unsigned short* __restrict__ bta,
    unsigned short* __restrict__ qp)
{
  __shared__ float wlds[27*96];
  __shared__ float gls[96], bls[96];
  __shared__ float ls1[29*12], ls2[29*12];
  __shared__ float lmean[29], linv[29];

  const int y  = blockIdx.x;
  const int t  = blockIdx.y;
  const int bh = blockIdx.z;
  const int tid = threadIdx.x;
  const bool has_cls = (y == 0 && t == 0);
  const unsigned short* base = qr + (size_t)bh*2408544;

  for (int idx = tid; idx < 27*96; idx += 384){
    int tap = idx / 96, d = idx - tap*96;
    wlds[idx] = b2f(cw[d*27 + tap]);
  }
  for (int idx = tid; idx < 96; idx += 384){
    gls[idx] = b2f(g[idx]); bls[idx] = b2f(bta[idx]);
  }
  __syncthreads();

  const int x = tid / 12, dg = tid - x*12;
  float val[8] = {0,0,0,0,0,0,0,0};

  if (x < 28){
    #pragma unroll
    for (int dt = 0; dt < 3; ++dt){
      int tt = t + dt - 1; if (tt < 0 || tt >= 8) continue;
      #pragma unroll
      for (int dy = 0; dy < 3; ++dy){
        int yy = 2*y + dy - 1; if (yy < 0 || yy >= 56) continue;
        #pragma unroll
        for (int dx = 0; dx < 3; ++dx){
          int xv = 2*x + dx - 1; if (xv < 0 || xv >= 56) continue;
          const int tap = (dt*3+dy)*3+dx;
          short8 v = *(const short8*)(base + (size_t)(1 + (tt*56 + yy)*56 + xv)*96 + dg*8);
          const float* wr = wlds + tap*96 + dg*8;
          #pragma unroll
          for (int j = 0; j < 8; ++j) val[j] += b2f((unsigned short)v[j]) * wr[j];
        }
      }
    }
    float s1 = 0.f, s2 = 0.f;
    #pragma unroll
    for (int j = 0; j < 8; ++j){ s1 += val[j]; s2 += val[j]*val[j]; }
    ls1[x*12+dg] = s1; ls2[x*12+dg] = s2;
  } else if (has_cls && tid >= 348 && tid < 360){
    int cdg = tid - 348;
    short8 v = *(const short8*)(base + cdg*8);
    float s1 = 0.f, s2 = 0.f;
    #pragma unroll
    for (int j = 0; j < 8; ++j){ val[j] = b2f((unsigned short)v[j]); s1 += val[j]; s2 += val[j]*val[j]; }
    ls1[28*12+cdg] = s1; ls2[28*12+cdg] = s2;
  }
  __syncthreads();

  if (tid < 28 || (tid == 28 && has_cls)){
    float s1 = 0.f, s2 = 0.f;
    #pragma unroll
    for (int k = 0; k < 12; ++k){ s1 += ls1[tid*12+k]; s2 += ls2[tid*12+k]; }
    float mean = s1 * (1.f/96.f);
    float var  = s2 * (1.f/96.f) - mean*mean;
    lmean[tid] = mean; linv[tid] = rsqrtf(var + 1e-5f);
  }
  __syncthreads();

  if (x < 28){
    float mean = lmean[x], inv = linv[x];
    int tok = 1 + (t*28 + y)*28 + x;
    short8 o;
    #pragma unroll
    for (int j = 0; j < 8; ++j)
      o[j] = (short)f2b((val[j] - mean)*inv*gls[dg*8+j] + bls[dg*8+j]);
    *(short8*)(qp + ((size_t)bh*6273 + tok)*96 + dg*8) = o;
  } else if (has_cls && tid >= 348 && tid < 360){
    int cdg = tid - 348;
    float mean = lmean[28], inv = linv[28];
    short8 o;
    #pragma unroll
    for (int j = 0; j < 8; ++j)
      o[j] = (short)f2b((val[j] - mean)*inv*gls[cdg*8+j] + bls[cdg*8+j]);
    *(short8*)(qp + (size_t)bh*6273*96 + cdg*8) = o;
  }
}

// ---------------- K3: k/v pooling (stride 1,8,8) + LN; v stored transposed ----------------
__global__ __launch_bounds__(128) void k_poolkv(
    const unsigned short* __restrict__ kr, const unsigned short* __restrict__ vr,
    const unsigned short* __restrict__ cwk, const unsigned short* __restrict__ gk, const unsigned short* __restrict__ bk,
    const unsigned short* __restrict__ cwv, const unsigned short* __restrict__ gv, const unsigned short* __restrict__ bv,
    unsigned short* __restrict__ kp, unsigned short* __restrict__ vt)
{
  const int bid = blockIdx.x;
  const int isv = blockIdx.y;
  const int bh = bid / 416; const int key = bid - bh*416;
  const int d = threadIdx.x;
  if (key >= 393){
    if (d < 96){
      if (isv == 0) kp[((size_t)bh*416 + key)*96 + d] = 0;
      else          vt[((size_t)bh*96 + d)*416 + key] = 0;
    }
    return;
  }
  const unsigned short* raw = (isv == 0 ? kr : vr) + (size_t)bh*2408544;
  const unsigned short* cw = (isv == 0) ? cwk : cwv;
  const unsigned short* g  = (isv == 0) ? gk : gv;
  const unsigned short* bt = (isv == 0) ? bk : bv;
  float val = 0.f;
  if (d < 96){
    if (key == 0) val = b2f(raw[d]);
    else {
      int s = key - 1; int t = s / 49; int r2 = s - t*49; int y = r2 / 7; int xx = r2 - y*7;
      const unsigned short* wr = cw + d*27;
      float sum = 0.f;
      for (int dt = 0; dt < 3; ++dt){
        int tt = t + dt - 1; if (tt < 0 || tt >= 8) continue;
        for (int dy = 0; dy < 3; ++dy){
          int yy = 8*y + dy - 1; if (yy < 0 || yy >= 56) continue;
          for (int dx = 0; dx < 3; ++dx){
            int xv = 8*xx + dx - 1; if (xv < 0 || xv >= 56) continue;
            sum += b2f(raw[(size_t)(1 + (tt*56 + yy)*56 + xv)*96 + d]) * b2f(wr[(dt*3+dy)*3+dx]);
          }
        }
      }
      val = sum;
    }
  }
  __shared__ float r1[128], r2s[128];
  r1[threadIdx.x] = (d < 96) ? val : 0.f;
  r2s[threadIdx.x] = (d < 96) ? val*val : 0.f;
  __syncthreads();
  for (int off = 64; off > 0; off >>= 1){
    if ((int)threadIdx.x < off){ r1[threadIdx.x] += r1[threadIdx.x+off]; r2s[threadIdx.x] += r2s[threadIdx.x+off]; }
    __syncthreads();
  }
  if (d < 96){
    float mean = r1[0] * (1.f/96.f);
    float var  = r2s[0] * (1.f/96.f) - mean*mean;
    float inv = rsqrtf(var + 1e-5f);
    float o = (val - mean)*inv*b2f(g[d]) + b2f(bt[d]);
    if (isv == 0) kp[((size_t)bh*416 + key)*96 + d] = f2b(o);
    else          vt[((size_t)bh*96 + d)*416 + key] = f2b(o);
  }
}

// ---------------- K3b: rel-pos dot table via MFMA: T[bh][q][128] fp16 ----------------
// cols 0..54 = Q·rph[row], 55..109 = Q·rpw[row-55], 110..124 = Q·rpt[row-110]
__global__ __launch_bounds__(256) void k_rel(
    const unsigned short* __restrict__ qp,
    const unsigned short* __restrict__ rph, const unsigned short* __restrict__ rpw,
    const unsigned short* __restrict__ rpt,
    _Float16* __restrict__ T)
{
  const int lane = threadIdx.x & 63;
  const int wv = threadIdx.x >> 6;
  const int bh = blockIdx.y;
  const int q0 = blockIdx.x*64 + wv*16;
  const int kq = (lane >> 4) * 8;
  const int col = lane & 15;

  const unsigned short* qbase = qp + (size_t)bh*6273*96;
  int qa = q0 + col; if (qa > 6272) qa = 6272;
  const unsigned short* qrow = qbase + (size_t)qa*96 + kq;
  short8 a0 = *(const short8*)(qrow);
  short8 a1 = *(const short8*)(qrow + 32);
  short8 a2 = *(const short8*)(qrow + 64);

  _Float16* Tb = T + (size_t)bh*6273*128;

  #pragma unroll
  for (int ct = 0; ct < 8; ++ct){
    int c = ct*16 + col;
    const unsigned short* rrow;
    if (c < 55)       rrow = rph + (size_t)c*96;
    else if (c < 110) rrow = rpw + (size_t)(c-55)*96;
    else { int ci = c-110; if (ci > 14) ci = 14; rrow = rpt + (size_t)ci*96; }
    rrow += kq;
    short8 b0 = *(const short8*)(rrow);
    short8 b1 = *(const short8*)(rrow + 32);
    short8 b2 = *(const short8*)(rrow + 64);
    floatx4 acc = {0.f,0.f,0.f,0.f};
    acc = __builtin_amdgcn_mfma_f32_16x16x32_bf16(a0, b0, acc, 0,0,0);
    acc = __builtin_amdgcn_mfma_f32_16x16x32_bf16(a1, b1, acc, 0,0,0);
    acc = __builtin_amdgcn_mfma_f32_16x16x32_bf16(a2, b2, acc, 0,0,0);
    #pragma unroll
    for (int r = 0; r < 4; ++r){
      int q = q0 + (lane >> 4)*4 + r;
      if (q <= 6272) Tb[(size_t)q*128 + ct*16 + col] = (_Float16)acc[r];
    }
  }
}

// ---------------- K4: fused attention — wave-independent, 64 q/block ----------------
// 4 waves; each wave owns 16 queries end-to-end. One barrier (stage T + coords),
// then no inter-wave sync. QK^T acc in 26 static floatx4 registers; softmax via
// quad shuffles; P in per-wave LDS strip (PSTR=424 → conflict-free b128 reads).
#define PSTR 424
__global__ __launch_bounds__(256) void k_attn(
    const unsigned short* __restrict__ qp, const unsigned short* __restrict__ kp,
    const unsigned short* __restrict__ vt, const _Float16* __restrict__ T,
    unsigned short* __restrict__ ao)
{
  __shared__ _Float16 Tlds[64*128];              // 16 KB
  __shared__ unsigned short P[4][16*PSTR];       // 54.3 KB
  __shared__ unsigned int coords[416];           // 1.7 KB

  const int bh = blockIdx.y;
  const int bb = bh >> 1, head = bh & 1;
  const int tid = threadIdx.x;
  const int lane = tid & 63;
  const int wv = tid >> 6;
  const int q0b = blockIdx.x * 64;
  const int q0 = q0b + wv*16;

  const unsigned short* qbase = qp + (size_t)bh*6273*96;
  const unsigned short* kbase = kp + (size_t)bh*416*96;
  const unsigned short* vbase = vt + (size_t)bh*96*416;

  // stage T tile: 64 rows x 128 fp16 (4 threads/row, 64B each)
  {
    int row = tid >> 2, ch = (tid & 3) * 32;
    int gq = q0b + row; if (gq > 6272) gq = 6272;
    const _Float16* src = T + ((size_t)bh*6273 + gq)*128 + ch;
    *(short8*)(Tlds + row*128 + ch)      = *(const short8*)(src);
    *(short8*)(Tlds + row*128 + ch + 8)  = *(const short8*)(src + 8);
    *(short8*)(Tlds + row*128 + ch + 16) = *(const short8*)(src + 16);
    *(short8*)(Tlds + row*128 + ch + 24) = *(const short8*)(src + 24);
  }
  // coords table
  for (int j = tid; j < 416; j += 256){
    unsigned int c;
    if (j == 0) c = 0u;
    else if (j >= 393) c = 2u << 24;
    else {
      int ks = j - 1; int kt = ks / 49; int krm = ks - kt*49; int ky = krm / 7; int kx = krm - ky*7;
      c = (unsigned)kt | ((unsigned)ky << 8) | ((unsigned)kx << 16) | (1u << 24);
    }
    coords[j] = c;
  }
  __syncthreads();
  // ---- wave-independent from here ----
  const int col = lane & 15;
  const int quad = lane >> 4;
  const int kq = quad * 8;

  // Q A-fragments
  short8 a0, a1, a2;
  {
    int qa = q0 + col; if (qa > 6272) qa = 6272;
    const unsigned short* qrow = qbase + (size_t)qa*96 + kq;
    a0 = *(const short8*)(qrow);
    a1 = *(const short8*)(qrow + 32);
    a2 = *(const short8*)(qrow + 64);
  }

  // QK^T: 26 key tiles, acc in registers (static indices only)
  floatx4 acc[26];
  #pragma unroll
  for (int t = 0; t < 26; ++t){
    const unsigned short* krow = kbase + (size_t)(t*16 + col)*96 + kq;
    short8 b0 = *(const short8*)(krow);
    short8 b1 = *(const short8*)(krow + 32);
    short8 b2 = *(const short8*)(krow + 64);
    floatx4 a = {0.f,0.f,0.f,0.f};
    a = __builtin_amdgcn_mfma_f32_16x16x32_bf16(a0, b0, a, 0,0,0);
    a = __builtin_amdgcn_mfma_f32_16x16x32_bf16(a1, b1, a, 0,0,0);
    a = __builtin_amdgcn_mfma_f32_16x16x32_bf16(a2, b2, a, 0,0,0);
    acc[t] = a;
  }

  // per-row rel bases (rows m = quad*4+r)
  int bhi[4], bwi[4], bti[4], liv[4];
  const _Float16* Tm[4];
  #pragma unroll
  for (int r = 0; r < 4; ++r){
    int gq = q0 + quad*4 + r;
    liv[r] = (gq >= 1 && gq <= 6272);
    int s = (gq >= 1) ? gq - 1 : 0;
    int tq = s / 784; int r2 = s - tq*784; int yq = r2 / 28; int xq = r2 - yq*28;
    bhi[r] = yq + 24; bwi[r] = 55 + xq + 24; bti[r] = 110 + tq + 7;
    Tm[r] = Tlds + (wv*16 + quad*4 + r)*128;
  }

  // rel add + scale; track max
  float mx[4] = {-1e30f, -1e30f, -1e30f, -1e30f};
  #pragma unroll
  for (int t = 0; t < 26; ++t){
    unsigned int c = coords[t*16 + col];
    unsigned int fl = c >> 24;
    int kt = c & 0xFF, ky = (c >> 8) & 0xFF, kx = (c >> 16) & 0xFF;
    #pragma unroll
    for (int r = 0; r < 4; ++r){
      float s;
      if (fl == 2u) s = -1e30f;
      else {
        s = acc[t][r] * SCALE_F;
        if (fl == 1u && liv[r])
          s += (float)Tm[r][bhi[r] - 4*ky] + (float)Tm[r][bwi[r] - 4*kx] + (float)Tm[r][bti[r] - kt];
      }
      acc[t][r] = s;
      mx[r] = fmaxf(mx[r], s);
    }
  }
  #pragma unroll
  for (int r = 0; r < 4; ++r){
    #pragma unroll
    for (int o = 1; o < 16; o <<= 1) mx[r] = fmaxf(mx[r], __shfl_xor(mx[r], o, 64));
  }
  float sum[4] = {0.f,0.f,0.f,0.f};
  #pragma unroll
  for (int t = 0; t < 26; ++t){
    #pragma unroll
    for (int r = 0; r < 4; ++r){
      float e = __expf(acc[t][r] - mx[r]);
      acc[t][r] = e; sum[r] += e;
    }
  }
  float linv[4];
  #pragma unroll
  for (int r = 0; r < 4; ++r){
    #pragma unroll
    for (int o = 1; o < 16; o <<= 1) sum[r] += __shfl_xor(sum[r], o, 64);
    linv[r] = 1.f / sum[r];
  }

  // write P strip (bf16, unnormalized)
  unsigned short* Pw = &P[wv][0];
  #pragma unroll
  for (int t = 0; t < 26; ++t){
    #pragma unroll
    for (int r = 0; r < 4; ++r){
      Pw[(quad*4 + r)*PSTR + t*16 + col] = f2b(acc[t][r]);
    }
  }

  // read A-fragments of P (same wave — ds ordering handled by compiler waitcnt)
  short8 pf[13];
  #pragma unroll
  for (int s = 0; s < 13; ++s)
    pf[s] = *(const short8*)(Pw + col*PSTR + s*32 + kq);

  // PV: 6 d-tiles × 13 MFMAs; epilogue: 1/sum + residual
  #pragma unroll
  for (int dt = 0; dt < 6; ++dt){
    const int dd = dt*16 + col;
    const unsigned short* vrow = vbase + (size_t)dd*416 + kq;
    floatx4 o = {0.f,0.f,0.f,0.f};
    #pragma unroll
    for (int s = 0; s < 13; ++s){
      short8 vf = *(const short8*)(vrow + s*32);
      o = __builtin_amdgcn_mfma_f32_16x16x32_bf16(pf[s], vf, o, 0,0,0);
    }
    #pragma unroll
    for (int r = 0; r < 4; ++r){
      int gq = q0 + quad*4 + r;
      if (gq <= 6272){
        float val = o[r] * linv[r] + b2f(qbase[(size_t)gq*96 + dd]);
        ao[((size_t)bb*6273 + gq)*192 + head*96 + dd] = f2b(val);
      }
    }
  }
}

// ---------------- K5: proj GEMM (flag-aware output dtype) ----------------
__global__ __launch_bounds__(256) void k_proj(
    const unsigned short* __restrict__ ao, const unsigned short* __restrict__ w,
    const unsigned short* __restrict__ bias, void* __restrict__ out, const int* __restrict__ flagp)
{
  const int flag = *flagp;
  const int lane = threadIdx.x & 63;
  const int wv = threadIdx.x >> 6;
  const int c = blockIdx.y*64 + wv*16 + (lane & 15);
  const int kq = (lane >> 4) * 8;
  short8 bfr[6];
  const unsigned short* wrow = w + c*192 + kq;
  #pragma unroll
  for (int s = 0; s < 6; ++s) bfr[s] = *(const short8*)(wrow + 32*s);
  float bv = b2f(bias[c]);
  const int m_base = blockIdx.x * 64;
  for (int i = 0; i < 4; ++i){
    int mt = m_base + i*16;
    int ma = mt + (lane & 15); if (ma > 25091) ma = 25091;
    const unsigned short* arow = ao + (size_t)ma*192 + kq;
    floatx4 acc = {0.f,0.f,0.f,0.f};
    #pragma unroll
    for (int s = 0; s < 6; ++s){
      short8 a = *(const short8*)(arow + 32*s);
      acc = __builtin_amdgcn_mfma_f32_16x16x32_bf16(a, bfr[s], acc, 0,0,0);
    }
    #pragma unroll
    for (int r = 0; r < 4; ++r){
      int m = mt + (lane >> 4)*4 + r;
      if (m < 25092){
        float o = acc[r] + bv;
        if (flag) ((float*)out)[(size_t)m*192 + c] = o;
        else      ((unsigned short*)out)[(size_t)m*192 + c] = f2b(o);
      }
    }
  }
}

extern "C" void kernel_launch(void* const* d_in, const int* in_sizes, int n_in,
                              void* d_out, int out_size, void* d_ws, size_t ws_size,
                              hipStream_t stream)
{
  char* p = (char*)d_ws;
  int* flagp = (int*)p; p += 16;
  unsigned short* conv = (unsigned short*)p;

  ConvDesc desc;
  long long cum = 0;
  for (int i = 0; i < 17; ++i){
    desc.src[i] = d_in[i];
    desc.off[i] = cum;
    desc.count[i] = in_sizes[i];
    cum += in_sizes[i];
  }
  p += (size_t)cum * 2;

  unsigned short* q_raw  = (unsigned short*)p; p += (size_t)19268352*2;
  unsigned short* k_raw  = (unsigned short*)p; p += (size_t)19268352*2;
  unsigned short* v_raw  = (unsigned short*)p; p += (size_t)19268352*2;
  unsigned short* q_pool = (unsigned short*)p; p += (size_t)4817664*2;
  unsigned short* k_pool = (unsigned short*)p; p += (size_t)319488*2;
  unsigned short* v_t    = (unsigned short*)p; p += (size_t)319488*2;
  _Float16*       T_rel  = (_Float16*)p;      p += (size_t)8*6273*128*2;
  unsigned short* a_out  = q_raw;   // q_raw dead after k_poolq

  const unsigned short* cx     = conv + desc.off[0];
  const unsigned short* cqkv_w = conv + desc.off[1];
  const unsigned short* cqkv_b = conv + desc.off[2];
  const unsigned short* cproj_w= conv + desc.off[3];
  const unsigned short* cproj_b= conv + desc.off[4];
  const unsigned short* cpq_w  = conv + desc.off[5];
  const unsigned short* cnq_g  = conv + desc.off[6];
  const unsigned short* cnq_b  = conv + desc.off[7];
  const unsigned short* cpk_w  = conv + desc.off[8];
  const unsigned short* cnk_g  = conv + desc.off[9];
  const unsigned short* cnk_b  = conv + desc.off[10];
  const unsigned short* cpv_w  = conv + desc.off[11];
  const unsigned short* cnv_g  = conv + desc.off[12];
  const unsigned short* cnv_b  = conv + desc.off[13];
  const unsigned short* crph   = conv + desc.off[14];
  const unsigned short* crpw   = conv + desc.off[15];
  const unsigned short* crpt   = conv + desc.off[16];

  k_convert<<<dim3(592, 17), 256, 0, stream>>>(desc, conv, flagp, (const unsigned int*)d_in[0]);
  k_qkv  <<<dim3(1569), 256, 0, stream>>>(cx, cqkv_w, cqkv_b, q_raw, k_raw, v_raw);
  k_poolq<<<dim3(28, 8, 8), 384, 0, stream>>>(q_raw, cpq_w, cnq_g, cnq_b, q_pool);
  k_poolkv<<<dim3(8*416, 2), 128, 0, stream>>>(k_raw, v_raw, cpk_w, cnk_g, cnk_b, cpv_w, cnv_g, cnv_b, k_pool, v_t);
  k_rel  <<<dim3(99, 8), 256, 0, stream>>>(q_pool, crph, crpw, crpt, T_rel);
  k_attn <<<dim3(99, 8), 256, 0, stream>>>(q_pool, k_pool, v_t, T_rel, a_out);
  k_proj <<<dim3(393, 3), 256, 0, stream>>>(a_out, cproj_w, cproj_b, d_out, flagp);
}

// Round 8
// 336.541 us; speedup vs baseline: 4.4528x; 1.0675x over previous
//
#include <hip/hip_runtime.h>
#include <hip/hip_bf16.h>

typedef short short8 __attribute__((ext_vector_type(8)));
typedef float floatx4 __attribute__((ext_vector_type(4)));
typedef float floatx4v __attribute__((ext_vector_type(4)));

#define SCALE_F 0.10206207261596575f

static __device__ __forceinline__ float b2f(unsigned short u){
  unsigned int v = ((unsigned int)u) << 16; float f;
  __builtin_memcpy(&f, &v, 4); return f;
}
static __device__ __forceinline__ unsigned short f2b(float f){
  __hip_bfloat16 h = __float2bfloat16(f);
  unsigned short u; __builtin_memcpy(&u, &h, 2); return u;
}
// compact-row index -> raw spatial coordinate (rows near multiples of 8)
static __device__ __forceinline__ int map20(int i){
  return (i < 2) ? i : 7 + ((i-2)/3)*8 + ((i-2)%3);
}

struct ConvDesc {
  const void* src[17];
  long long off[17];
  int count[17];
};

// ---------------- K0: dtype detect + convert all float tensors to bf16 ----------------
__global__ __launch_bounds__(256) void k_convert(ConvDesc d, unsigned short* dst_base,
                                                 int* flagp, const unsigned int* xprobe)
{
  __shared__ int sflag;
  if (threadIdx.x < 64){
    unsigned int w = xprobe[1024 + threadIdx.x];
    int e = (w >> 7) & 0xFF;
    int pl = (e >= 90 && e <= 140) ? 1 : 0;
    unsigned long long m = __ballot(pl);
    if (threadIdx.x == 0){
      sflag = (__popcll(m) < 40) ? 1 : 0;   // 1 = inputs are fp32
      if (blockIdx.x == 0 && blockIdx.y == 0) *flagp = sflag;
    }
  }
  __syncthreads();
  const int flag = sflag;
  const int t = blockIdx.y;
  const int cnt = d.count[t];
  unsigned short* dst = dst_base + d.off[t];
  const float* sf = (const float*)d.src[t];
  const unsigned short* su = (const unsigned short*)d.src[t];
  for (int i = blockIdx.x*blockDim.x + threadIdx.x; i < cnt; i += gridDim.x*blockDim.x){
    dst[i] = flag ? f2b(sf[i]) : su[i];
  }
}

// ---------------- K1a: Q-columns GEMM (all tokens, cols 0..191) ----------------
__global__ __launch_bounds__(256) void k_qkv_q(
    const unsigned short* __restrict__ x, const unsigned short* __restrict__ w,
    const unsigned short* __restrict__ bias, unsigned short* __restrict__ qr)
{
  const int lane = threadIdx.x & 63;
  const int wv = threadIdx.x >> 6;
  const int kq = (lane >> 4) * 8;
  const int m_base = blockIdx.x * 64 + wv * 16;

  int ma = m_base + (lane & 15); if (ma > 100355) ma = 100355;
  const unsigned short* xrow = x + (size_t)ma*96 + kq;
  short8 a0 = *(const short8*)(xrow);
  short8 a1 = *(const short8*)(xrow + 32);
  short8 a2 = *(const short8*)(xrow + 64);

  size_t base0[4];
  int mrow[4];
  #pragma unroll
  for (int r = 0; r < 4; ++r){
    int m = m_base + (lane >> 4)*4 + r;
    mrow[r] = m;
    int bb = m / 25089; int n = m - bb*25089;
    base0[r] = ((size_t)(bb*2)*25089 + n)*96;
  }

  #pragma unroll
  for (int ct = 0; ct < 12; ++ct){
    int col = ct*16 + (lane & 15);
    const unsigned short* wrow = w + col*96 + kq;
    short8 b0 = *(const short8*)(wrow);
    short8 b1 = *(const short8*)(wrow + 32);
    short8 b2 = *(const short8*)(wrow + 64);
    float bv = b2f(bias[col]);
    floatx4 acc = {0.f,0.f,0.f,0.f};
    acc = __builtin_amdgcn_mfma_f32_16x16x32_bf16(a0, b0, acc, 0,0,0);
    acc = __builtin_amdgcn_mfma_f32_16x16x32_bf16(a1, b1, acc, 0,0,0);
    acc = __builtin_amdgcn_mfma_f32_16x16x32_bf16(a2, b2, acc, 0,0,0);
    const int head = ct / 6;
    const int dstat = (ct % 6) * 16;
    size_t hoff = (size_t)head * 2408544 + dstat + (lane & 15);
    #pragma unroll
    for (int r = 0; r < 4; ++r){
      if (mrow[r] < 100356) qr[base0[r] + hoff] = f2b(acc[r] + bv);
    }
  }
}

// ---------------- K1b: KV-columns GEMM (gathered ~12.8k tokens, cols 192..575) ------
// row rho: 0..3 = cls token of batch rho; 4.. = (b,t,ry,rx) gathered spatial rows.
// outputs: kc/vc[(((b*8+t)*20+ry)*20+rx)*192 + head*96 + d]; kcls/vcls[(b*2+head)*96+d]
__global__ __launch_bounds__(256) void k_qkv_kv(
    const unsigned short* __restrict__ x, const unsigned short* __restrict__ w,
    const unsigned short* __restrict__ bias,
    unsigned short* __restrict__ kc, unsigned short* __restrict__ vc,
    unsigned short* __restrict__ kcls, unsigned short* __restrict__ vcls)
{
  const int lane = threadIdx.x & 63;
  const int wv = threadIdx.x >> 6;
  const int kq = (lane >> 4) * 8;
  const int quad = lane >> 4;
  const int col_l = lane & 15;
  const int rbase = blockIdx.x * 64 + wv * 16;

  // A-fragment row (load side)
  int rhoA = rbase + col_l; if (rhoA > 12803) rhoA = 12803;
  int bA, nA;
  if (rhoA < 4){ bA = rhoA; nA = 0; }
  else {
    int rp = rhoA - 4;
    bA = rp / 3200; int rem = rp - bA*3200;
    int t = rem / 400; int s = rem - t*400;
    int ry = s / 20, rx = s - ry*20;
    nA = 1 + (t*56 + map20(ry))*56 + map20(rx);
  }
  const unsigned short* xrow = x + ((size_t)bA*25089 + nA)*96 + kq;
  short8 a0 = *(const short8*)(xrow);
  short8 a1 = *(const short8*)(xrow + 32);
  short8 a2 = *(const short8*)(xrow + 64);

  // C-layout rows (store side)
  int isCls[4], bI[4], baseI[4], valid[4];
  #pragma unroll
  for (int r = 0; r < 4; ++r){
    int rho = rbase + quad*4 + r;
    valid[r] = (rho < 12804);
    if (rho > 12803) rho = 12803;
    if (rho < 4){ isCls[r] = 1; bI[r] = rho; baseI[r] = 0; }
    else {
      int rp = rho - 4;
      int b = rp / 3200; int rem = rp - b*3200;
      int t = rem / 400; int s = rem - t*400;
      int ry = s / 20, rx = s - ry*20;
      isCls[r] = 0; bI[r] = b;
      baseI[r] = (((b*8 + t)*20 + ry)*20 + rx)*192;
    }
  }

  #pragma unroll
  for (int ct = 0; ct < 24; ++ct){
    const int col = 192 + ct*16 + col_l;
    const unsigned short* wrow = w + col*96 + kq;
    short8 b0 = *(const short8*)(wrow);
    short8 b1 = *(const short8*)(wrow + 32);
    short8 b2 = *(const short8*)(wrow + 64);
    float bv = b2f(bias[col]);
    floatx4 acc = {0.f,0.f,0.f,0.f};
    acc = __builtin_amdgcn_mfma_f32_16x16x32_bf16(a0, b0, acc, 0,0,0);
    acc = __builtin_amdgcn_mfma_f32_16x16x32_bf16(a1, b1, acc, 0,0,0);
    acc = __builtin_amdgcn_mfma_f32_16x16x32_bf16(a2, b2, acc, 0,0,0);
    const int isv = (ct >= 12);
    const int cti = isv ? ct - 12 : ct;
    const int head = cti / 6;
    const int dstat = (cti % 6) * 16;
    unsigned short* buf  = isv ? vc : kc;
    unsigned short* bufc = isv ? vcls : kcls;
    #pragma unroll
    for (int r = 0; r < 4; ++r){
      if (valid[r]){
        float o = acc[r] + bv;
        if (isCls[r]) bufc[(bI[r]*2 + head)*96 + dstat + col_l] = f2b(o);
        else          buf[baseI[r] + head*96 + dstat + col_l]   = f2b(o);
      }
    }
  }
}

// ---------------- K2: q pooling (stride 1,2,2) + LN ----------
__global__ __launch_bounds__(384) void k_poolq(
    const unsigned short* __restrict__ qr, const unsigned short* __restrict__ cw,
    const unsigned short* __restrict__ g, const unsigned short* __restrict__ bta,
    unsigned short* __restrict__ qp)
{
  __shared__ float wlds[27*96];
  __shared__ float gls[96], bls[96];
  __shared__ float ls1[29*12], ls2[29*12];
  __shared__ float lmean[29], linv[29];

  const int y  = blockIdx.x;
  const int t  = blockIdx.y;
  const int bh = blockIdx.z;
  const int tid = threadIdx.x;
  const bool has_cls = (y == 0 && t == 0);
  const unsigned short* base = qr + (size_t)bh*2408544;

  for (int idx = tid; idx < 27*96; idx += 384){
    int tap = idx / 96, d = idx - tap*96;
    wlds[idx] = b2f(cw[d*27 + tap]);
  }
  for (int idx = tid; idx < 96; idx += 384){
    gls[idx] = b2f(g[idx]); bls[idx] = b2f(bta[idx]);
  }
  __syncthreads();

  const int x = tid / 12, dg = tid - x*12;
  float val[8] = {0,0,0,0,0,0,0,0};

  if (x < 28){
    #pragma unroll
    for (int dt = 0; dt < 3; ++dt){
      int tt = t + dt - 1; if (tt < 0 || tt >= 8) continue;
      #pragma unroll
      for (int dy = 0; dy < 3; ++dy){
        int yy = 2*y + dy - 1; if (yy < 0 || yy >= 56) continue;
        #pragma unroll
        for (int dx = 0; dx < 3; ++dx){
          int xv = 2*x + dx - 1; if (xv < 0 || xv >= 56) continue;
          const int tap = (dt*3+dy)*3+dx;
          short8 v = *(const short8*)(base + (size_t)(1 + (tt*56 + yy)*56 + xv)*96 + dg*8);
          const float* wr = wlds + tap*96 + dg*8;
          #pragma unroll
          for (int j = 0; j < 8; ++j) val[j] += b2f((unsigned short)v[j]) * wr[j];
        }
      }
    }
    float s1 = 0.f, s2 = 0.f;
    #pragma unroll
    for (int j = 0; j < 8; ++j){ s1 += val[j]; s2 += val[j]*val[j]; }
    ls1[x*12+dg] = s1; ls2[x*12+dg] = s2;
  } else if (has_cls && tid >= 348 && tid < 360){
    int cdg = tid - 348;
    short8 v = *(const short8*)(base + cdg*8);
    float s1 = 0.f, s2 = 0.f;
    #pragma unroll
    for (int j = 0; j < 8; ++j){ val[j] = b2f((unsigned short)v[j]); s1 += val[j]; s2 += val[j]*val[j]; }
    ls1[28*12+cdg] = s1; ls2[28*12+cdg] = s2;
  }
  __syncthreads();

  if (tid < 28 || (tid == 28 && has_cls)){
    float s1 = 0.f, s2 = 0.f;
    #pragma unroll
    for (int k = 0; k < 12; ++k){ s1 += ls1[tid*12+k]; s2 += ls2[tid*12+k]; }
    float mean = s1 * (1.f/96.f);
    float var  = s2 * (1.f/96.f) - mean*mean;
    lmean[tid] = mean; linv[tid] = rsqrtf(var + 1e-5f);
  }
  __syncthreads();

  if (x < 28){
    float mean = lmean[x], inv = linv[x];
    int tok = 1 + (t*28 + y)*28 + x;
    short8 o;
    #pragma unroll
    for (int j = 0; j < 8; ++j)
      o[j] = (short)f2b((val[j] - mean)*inv*gls[dg*8+j] + bls[dg*8+j]);
    *(short8*)(qp + ((size_t)bh*6273 + tok)*96 + dg*8) = o;
  } else if (has_cls && tid >= 348 && tid < 360){
    int cdg = tid - 348;
    float mean = lmean[28], inv = linv[28];
    short8 o;
    #pragma unroll
    for (int j = 0; j < 8; ++j)
      o[j] = (short)f2b((val[j] - mean)*inv*gls[cdg*8+j] + bls[cdg*8+j]);
    *(short8*)(qp + (size_t)bh*6273*96 + cdg*8) = o;
  }
}

// ---------------- K3: k/v pooling from compact buffers + LN; v transposed ----------
__global__ __launch_bounds__(128) void k_poolkv(
    const unsigned short* __restrict__ kc, const unsigned short* __restrict__ vc,
    const unsigned short* __restrict__ kcls, const unsigned short* __restrict__ vcls,
    const unsigned short* __restrict__ cwk, const unsigned short* __restrict__ gk, const unsigned short* __restrict__ bk,
    const unsigned short* __restrict__ cwv, const unsigned short* __restrict__ gv, const unsigned short* __restrict__ bv,
    unsigned short* __restrict__ kp, unsigned short* __restrict__ vt)
{
  const int bid = blockIdx.x;
  const int isv = blockIdx.y;
  const int bh = bid / 416; const int key = bid - bh*416;
  const int d = threadIdx.x;
  if (key >= 393){
    if (d < 96){
      if (isv == 0) kp[((size_t)bh*416 + key)*96 + d] = 0;
      else          vt[((size_t)bh*96 + d)*416 + key] = 0;
    }
    return;
  }
  const int b = bh >> 1, head = bh & 1;
  const unsigned short* buf  = isv ? vc : kc;
  const unsigned short* bufc = isv ? vcls : kcls;
  const unsigned short* cw = (isv == 0) ? cwk : cwv;
  const unsigned short* g  = (isv == 0) ? gk : gv;
  const unsigned short* bt = (isv == 0) ? bk : bv;
  float val = 0.f;
  if (d < 96){
    if (key == 0) val = b2f(bufc[bh*96 + d]);
    else {
      int s = key - 1; int t = s / 49; int r2 = s - t*49; int y = r2 / 7; int xx = r2 - y*7;
      const unsigned short* wr = cw + d*27;
      float sum = 0.f;
      #pragma unroll
      for (int dt = 0; dt < 3; ++dt){
        int tt = t + dt - 1; if (tt < 0 || tt >= 8) continue;
        #pragma unroll
        for (int dy = 0; dy < 3; ++dy){
          if (y == 0 && dy == 0) continue;          // yy = -1
          int ry = (y == 0) ? (dy - 1) : 2 + 3*(y-1) + dy;
          #pragma unroll
          for (int dx = 0; dx < 3; ++dx){
            if (xx == 0 && dx == 0) continue;       // xv = -1
            int rx = (xx == 0) ? (dx - 1) : 2 + 3*(xx-1) + dx;
            sum += b2f(buf[(((b*8 + tt)*20 + ry)*20 + rx)*192 + head*96 + d]) * b2f(wr[(dt*3+dy)*3+dx]);
          }
        }
      }
      val = sum;
    }
  }
  __shared__ float r1[128], r2s[128];
  r1[threadIdx.x] = (d < 96) ? val : 0.f;
  r2s[threadIdx.x] = (d < 96) ? val*val : 0.f;
  __syncthreads();
  for (int off = 64; off > 0; off >>= 1){
    if ((int)threadIdx.x < off){ r1[threadIdx.x] += r1[threadIdx.x+off]; r2s[threadIdx.x] += r2s[threadIdx.x+off]; }
    __syncthreads();
  }
  if (d < 96){
    float mean = r1[0] * (1.f/96.f);
    float var  = r2s[0] * (1.f/96.f) - mean*mean;
    float inv = rsqrtf(var + 1e-5f);
    float o = (val - mean)*inv*b2f(g[d]) + b2f(bt[d]);
    if (isv == 0) kp[((size_t)bh*416 + key)*96 + d] = f2b(o);
    else          vt[((size_t)bh*96 + d)*416 + key] = f2b(o);
  }
}

// ---------------- K3b: rel-pos compact table: Trel[bh][q][24] float ----------------
// slots 0..6 = dh[ky], 8..14 = dw[kx], 16..23 = dt[kt]
__global__ __launch_bounds__(256) void k_rel(
    const unsigned short* __restrict__ qp,
    const unsigned short* __restrict__ rph, const unsigned short* __restrict__ rpw,
    const unsigned short* __restrict__ rpt,
    float* __restrict__ Trel)
{
  const int lane = threadIdx.x & 63;
  const int wv = threadIdx.x >> 6;
  const int bh = blockIdx.y;
  const int q0 = blockIdx.x*64 + wv*16;
  const int kq = (lane >> 4) * 8;
  const int quad = lane >> 4;
  const int col_l = lane & 15;

  const unsigned short* qbase = qp + (size_t)bh*6273*96;
  int qa = q0 + col_l; if (qa > 6272) qa = 6272;
  const unsigned short* qrow = qbase + (size_t)qa*96 + kq;
  short8 a0 = *(const short8*)(qrow);
  short8 a1 = *(const short8*)(qrow + 32);
  short8 a2 = *(const short8*)(qrow + 64);

  // per-row coords
  int yq[4], xq[4], tq[4], liv[4];
  #pragma unroll
  for (int r = 0; r < 4; ++r){
    int gq = q0 + quad*4 + r;
    liv[r] = (gq >= 1 && gq <= 6272);
    int s = (gq >= 1) ? gq - 1 : 0;
    tq[r] = s / 784; int r2 = s - tq[r]*784; yq[r] = r2 / 28; xq[r] = r2 - yq[r]*28;
  }
  float* Tb = Trel + (size_t)bh*6273*24;

  #pragma unroll
  for (int ct = 0; ct < 8; ++ct){
    int c = ct*16 + col_l;
    const unsigned short* rrow;
    if (c < 55)       rrow = rph + (size_t)c*96;
    else if (c < 110) rrow = rpw + (size_t)(c-55)*96;
    else { int ci = c-110; if (ci > 14) ci = 14; rrow = rpt + (size_t)ci*96; }
    rrow += kq;
    short8 b0 = *(const short8*)(rrow);
    short8 b1 = *(const short8*)(rrow + 32);
    short8 b2 = *(const short8*)(rrow + 64);
    floatx4 acc = {0.f,0.f,0.f,0.f};
    acc = __builtin_amdgcn_mfma_f32_16x16x32_bf16(a0, b0, acc, 0,0,0);
    acc = __builtin_amdgcn_mfma_f32_16x16x32_bf16(a1, b1, acc, 0,0,0);
    acc = __builtin_amdgcn_mfma_f32_16x16x32_bf16(a2, b2, acc, 0,0,0);
    #pragma unroll
    for (int r = 0; r < 4; ++r){
      int gq = q0 + quad*4 + r;
      if (!liv[r] || gq > 6272) continue;
      float* Tq = Tb + (size_t)gq*24;
      if (c < 55){
        int u = yq[r] + 24 - c;
        if (u >= 0 && u <= 24 && (u & 3) == 0) Tq[u >> 2] = acc[r];
      } else if (c < 110){
        int u = xq[r] + 24 - (c - 55);
        if (u >= 0 && u <= 24 && (u & 3) == 0) Tq[8 + (u >> 2)] = acc[r];
      } else if (c < 125){
        int u = tq[r] + 7 - (c - 110);
        if (u >= 0 && u <= 7) Tq[16 + u] = acc[r];
      }
    }
  }
}

// ---------------- K4: fused attention — flash 2-pass, wave-independent ----------------
// 4 waves x 16 q; one staging barrier; per-wave P strip. LDS ~37.5 KB -> 4 blocks/CU.
#define PSTR 232
__global__ __launch_bounds__(256) void k_attn(
    const unsigned short* __restrict__ qp, const unsigned short* __restrict__ kp,
    const unsigned short* __restrict__ vt, const float* __restrict__ Trel,
    unsigned short* __restrict__ ao)
{
  __shared__ float rel[64*24];                   // 6 KB
  __shared__ unsigned short P[4][16*PSTR];       // 29.7 KB
  __shared__ unsigned int coords[416];           // 1.7 KB

  const int bh = blockIdx.y;
  const int bb = bh >> 1, head = bh & 1;
  const int tid = threadIdx.x;
  const int lane = tid & 63;
  const int wv = tid >> 6;
  const int q0b = blockIdx.x * 64;
  const int q0 = q0b + wv*16;

  const unsigned short* qbase = qp + (size_t)bh*6273*96;
  const unsigned short* kbase = kp + (size_t)bh*416*96;
  const unsigned short* vbase = vt + (size_t)bh*96*416;

  // stage rel table: 64 rows x 24 floats (coalesced float4)
  for (int idx = tid; idx < 64*6; idx += 256){
    int row = idx / 6, seg = idx - row*6;
    int gq = q0b + row; if (gq > 6272) gq = 6272;
    *(floatx4v*)(rel + row*24 + seg*4) =
      *(const floatx4v*)(Trel + ((size_t)bh*6273 + gq)*24 + seg*4);
  }
  for (int j = tid; j < 416; j += 256){
    unsigned int c;
    if (j == 0) c = 0u;
    else if (j >= 393) c = 2u << 24;
    else {
      int ks = j - 1; int kt = ks / 49; int krm = ks - kt*49; int ky = krm / 7; int kx = krm - ky*7;
      c = (unsigned)kt | ((unsigned)ky << 8) | ((unsigned)kx << 16) | (1u << 24);
    }
    coords[j] = c;
  }
  __syncthreads();
  // ---- wave-independent from here ----
  const int col = lane & 15;
  const int quad = lane >> 4;
  const int kq = quad * 8;

  short8 a0, a1, a2;
  {
    int qa = q0 + col; if (qa > 6272) qa = 6272;
    const unsigned short* qrow = qbase + (size_t)qa*96 + kq;
    a0 = *(const short8*)(qrow);
    a1 = *(const short8*)(qrow + 32);
    a2 = *(const short8*)(qrow + 64);
  }

  int liv[4];
  const float* Tm[4];
  #pragma unroll
  for (int r = 0; r < 4; ++r){
    int gq = q0 + quad*4 + r;
    liv[r] = (gq >= 1 && gq <= 6272);
    Tm[r] = rel + (wv*16 + quad*4 + r)*24;
  }
  unsigned short* Pw = &P[wv][0];
  floatx4 o0={0,0,0,0}, o1={0,0,0,0}, o2={0,0,0,0}, o3={0,0,0,0}, o4={0,0,0,0}, o5={0,0,0,0};
  float mx1[4] = {-1e30f,-1e30f,-1e30f,-1e30f};
  float l1[4] = {0.f,0.f,0.f,0.f};

  // ======== PASS 1: key tiles 0..13 (keys 0..223) ========
  {
    floatx4 acc[14];
    #pragma unroll
    for (int t = 0; t < 14; ++t){
      const unsigned short* krow = kbase + (size_t)(t*16 + col)*96 + kq;
      short8 b0 = *(const short8*)(krow);
      short8 b1 = *(const short8*)(krow + 32);
      short8 b2 = *(const short8*)(krow + 64);
      floatx4 a = {0.f,0.f,0.f,0.f};
      a = __builtin_amdgcn_mfma_f32_16x16x32_bf16(a0, b0, a, 0,0,0);
      a = __builtin_amdgcn_mfma_f32_16x16x32_bf16(a1, b1, a, 0,0,0);
      a = __builtin_amdgcn_mfma_f32_16x16x32_bf16(a2, b2, a, 0,0,0);
      acc[t] = a;
    }
    #pragma unroll
    for (int t = 0; t < 14; ++t){
      unsigned int c = coords[t*16 + col];
      unsigned int fl = c >> 24;
      int kt = c & 0xFF, ky = (c >> 8) & 0xFF, kx = (c >> 16) & 0xFF;
      #pragma unroll
      for (int r = 0; r < 4; ++r){
        float s = acc[t][r] * SCALE_F;
        if (fl == 1u && liv[r])
          s += Tm[r][ky] + Tm[r][8 + kx] + Tm[r][16 + kt];
        acc[t][r] = s;
        mx1[r] = fmaxf(mx1[r], s);
      }
    }
    #pragma unroll
    for (int r = 0; r < 4; ++r){
      #pragma unroll
      for (int o = 1; o < 16; o <<= 1) mx1[r] = fmaxf(mx1[r], __shfl_xor(mx1[r], o, 64));
    }
    #pragma unroll
    for (int t = 0; t < 14; ++t){
      #pragma unroll
      for (int r = 0; r < 4; ++r){
        float e = __expf(acc[t][r] - mx1[r]);
        acc[t][r] = e; l1[r] += e;
      }
    }
    #pragma unroll
    for (int r = 0; r < 4; ++r){
      #pragma unroll
      for (int o = 1; o < 16; o <<= 1) l1[r] += __shfl_xor(l1[r], o, 64);
    }
    #pragma unroll
    for (int t = 0; t < 14; ++t){
      #pragma unroll
      for (int r = 0; r < 4; ++r)
        Pw[(quad*4 + r)*PSTR + t*16 + col] = f2b(acc[t][r]);
    }
  }
  // PV1: keys 0..223 (7 k-steps)
  {
    short8 pf[7];
    #pragma unroll
    for (int s = 0; s < 7; ++s)
      pf[s] = *(const short8*)(Pw + col*PSTR + s*32 + kq);
    #pragma unroll
    for (int dt = 0; dt < 6; ++dt){
      const int dd = dt*16 + col;
      const unsigned short* vrow = vbase + (size_t)dd*416 + kq;
      floatx4 o = {0.f,0.f,0.f,0.f};
      #pragma unroll
      for (int s = 0; s < 7; ++s){
        short8 vf = *(const short8*)(vrow + s*32);
        o = __builtin_amdgcn_mfma_f32_16x16x32_bf16(pf[s], vf, o, 0,0,0);
      }
      if (dt == 0) o0 = o; else if (dt == 1) o1 = o; else if (dt == 2) o2 = o;
      else if (dt == 3) o3 = o; else if (dt == 4) o4 = o; else o5 = o;
    }
  }

  // ======== PASS 2: key tiles 14..25 (keys 224..415) ========
  float lt[4];
  {
    floatx4 acc[12];
    #pragma unroll
    for (int t = 0; t < 12; ++t){
      const unsigned short* krow = kbase + (size_t)((t+14)*16 + col)*96 + kq;
      short8 b0 = *(const short8*)(krow);
      short8 b1 = *(const short8*)(krow + 32);
      short8 b2 = *(const short8*)(krow + 64);
      floatx4 a = {0.f,0.f,0.f,0.f};
      a = __builtin_amdgcn_mfma_f32_16x16x32_bf16(a0, b0, a, 0,0,0);
      a = __builtin_amdgcn_mfma_f32_16x16x32_bf16(a1, b1, a, 0,0,0);
      a = __builtin_amdgcn_mfma_f32_16x16x32_bf16(a2, b2, a, 0,0,0);
      acc[t] = a;
    }
    float mx2[4] = {-1e30f,-1e30f,-1e30f,-1e30f};
    #pragma unroll
    for (int t = 0; t < 12; ++t){
      unsigned int c = coords[(t+14)*16 + col];
      unsigned int fl = c >> 24;
      int kt = c & 0xFF, ky = (c >> 8) & 0xFF, kx = (c >> 16) & 0xFF;
      #pragma unroll
      for (int r = 0; r < 4; ++r){
        float s;
        if (fl == 2u) s = -1e30f;
        else {
          s = acc[t][r] * SCALE_F;
          if (liv[r]) s += Tm[r][ky] + Tm[r][8 + kx] + Tm[r][16 + kt];
        }
        acc[t][r] = s;
        mx2[r] = fmaxf(mx2[r], s);
      }
    }
    #pragma unroll
    for (int r = 0; r < 4; ++r){
      #pragma unroll
      for (int o = 1; o < 16; o <<= 1) mx2[r] = fmaxf(mx2[r], __shfl_xor(mx2[r], o, 64));
    }
    float M[4], a1s[4], l2[4] = {0.f,0.f,0.f,0.f};
    #pragma unroll
    for (int r = 0; r < 4; ++r){
      M[r] = fmaxf(mx1[r], mx2[r]);
      a1s[r] = __expf(mx1[r] - M[r]);
    }
    #pragma unroll
    for (int t = 0; t < 12; ++t){
      #pragma unroll
      for (int r = 0; r < 4; ++r){
        float e = __expf(acc[t][r] - M[r]);
        acc[t][r] = e; l2[r] += e;
      }
    }
    #pragma unroll
    for (int r = 0; r < 4; ++r){
      #pragma unroll
      for (int o = 1; o < 16; o <<= 1) l2[r] += __shfl_xor(l2[r], o, 64);
      lt[r] = l1[r]*a1s[r] + l2[r];
    }
    // rescale O by a1s (per-row r)
    #pragma unroll
    for (int r = 0; r < 4; ++r){
      o0[r] *= a1s[r]; o1[r] *= a1s[r]; o2[r] *= a1s[r];
      o3[r] *= a1s[r]; o4[r] *= a1s[r]; o5[r] *= a1s[r];
    }
    #pragma unroll
    for (int t = 0; t < 12; ++t){
      #pragma unroll
      for (int r = 0; r < 4; ++r)
        Pw[(quad*4 + r)*PSTR + t*16 + col] = f2b(acc[t][r]);
    }
  }
  // PV2: keys 224..415 (6 k-steps)
  {
    short8 pf[6];
    #pragma unroll
    for (int s = 0; s < 6; ++s)
      pf[s] = *(const short8*)(Pw + col*PSTR + s*32 + kq);
    #pragma unroll
    for (int dt = 0; dt < 6; ++dt){
      const int dd = dt*16 + col;
      const unsigned short* vrow = vbase + (size_t)dd*416 + 224 + kq;
      floatx4 o;
      if (dt == 0) o = o0; else if (dt == 1) o = o1; else if (dt == 2) o = o2;
      else if (dt == 3) o = o3; else if (dt == 4) o = o4; else o = o5;
      #pragma unroll
      for (int s = 0; s < 6; ++s){
        short8 vf = *(const short8*)(vrow + s*32);
        o = __builtin_amdgcn_mfma_f32_16x16x32_bf16(pf[s], vf, o, 0,0,0);
      }
      float inv4[4];
      #pragma unroll
      for (int r = 0; r < 4; ++r) inv4[r] = 1.f / lt[r];
      #pragma unroll
      for (int r = 0; r < 4; ++r){
        int gq = q0 + quad*4 + r;
        if (gq <= 6272){
          float val = o[r] * inv4[r] + b2f(qbase[(size_t)gq*96 + dd]);
          ao[((size_t)bb*6273 + gq)*192 + head*96 + dd] = f2b(val);
        }
      }
    }
  }
}

// ---------------- K5: proj GEMM (flag-aware output dtype) ----------------
__global__ __launch_bounds__(256) void k_proj(
    const unsigned short* __restrict__ ao, const unsigned short* __restrict__ w,
    const unsigned short* __restrict__ bias, void* __restrict__ out, const int* __restrict__ flagp)
{
  const int flag = *flagp;
  const int lane = threadIdx.x & 63;
  const int wv = threadIdx.x >> 6;
  const int c = blockIdx.y*64 + wv*16 + (lane & 15);
  const int kq = (lane >> 4) * 8;
  short8 bfr[6];
  const unsigned short* wrow = w + c*192 + kq;
  #pragma unroll
  for (int s = 0; s < 6; ++s) bfr[s] = *(const short8*)(wrow + 32*s);
  float bv = b2f(bias[c]);
  const int m_base = blockIdx.x * 64;
  for (int i = 0; i < 4; ++i){
    int mt = m_base + i*16;
    int ma = mt + (lane & 15); if (ma > 25091) ma = 25091;
    const unsigned short* arow = ao + (size_t)ma*192 + kq;
    floatx4 acc = {0.f,0.f,0.f,0.f};
    #pragma unroll
    for (int s = 0; s < 6; ++s){
      short8 a = *(const short8*)(arow + 32*s);
      acc = __builtin_amdgcn_mfma_f32_16x16x32_bf16(a, bfr[s], acc, 0,0,0);
    }
    #pragma unroll
    for (int r = 0; r < 4; ++r){
      int m = mt + (lane >> 4)*4 + r;
      if (m < 25092){
        float o = acc[r] + bv;
        if (flag) ((float*)out)[(size_t)m*192 + c] = o;
        else      ((unsigned short*)out)[(size_t)m*192 + c] = f2b(o);
      }
    }
  }
}

extern "C" void kernel_launch(void* const* d_in, const int* in_sizes, int n_in,
                              void* d_out, int out_size, void* d_ws, size_t ws_size,
                              hipStream_t stream)
{
  char* p = (char*)d_ws;
  int* flagp = (int*)p; p += 16;
  unsigned short* conv = (unsigned short*)p;

  ConvDesc desc;
  long long cum = 0;
  for (int i = 0; i < 17; ++i){
    desc.src[i] = d_in[i];
    desc.off[i] = cum;
    desc.count[i] = in_sizes[i];
    cum += in_sizes[i];
  }
  p += (size_t)cum * 2;

  unsigned short* q_raw  = (unsigned short*)p; p += (size_t)19268352*2;
  unsigned short* kc     = (unsigned short*)p; p += (size_t)2457600*2;
  unsigned short* vc     = (unsigned short*)p; p += (size_t)2457600*2;
  unsigned short* kcls   = (unsigned short*)p; p += (size_t)768*2;
  unsigned short* vcls   = (unsigned short*)p; p += (size_t)768*2;
  unsigned short* q_pool = (unsigned short*)p; p += (size_t)4817664*2;
  unsigned short* k_pool = (unsigned short*)p; p += (size_t)319488*2;
  unsigned short* v_t    = (unsigned short*)p; p += (size_t)319488*2;
  float*          Trel   = (float*)p;         p += (size_t)8*6273*24*4;
  unsigned short* a_out  = q_raw;   // q_raw dead after k_poolq

  const unsigned short* cx     = conv + desc.off[0];
  const unsigned short* cqkv_w = conv + desc.off[1];
  const unsigned short* cqkv_b = conv + desc.off[2];
  const unsigned short* cproj_w= conv + desc.off[3];
  const unsigned short* cproj_b= conv + desc.off[4];
  const unsigned short* cpq_w  = conv + desc.off[5];
  const unsigned short* cnq_g  = conv + desc.off[6];
  const unsigned short* cnq_b  = conv + desc.off[7];
  const unsigned short* cpk_w  = conv + desc.off[8];
  const unsigned short* cnk_g  = conv + desc.off[9];
  const unsigned short* cnk_b  = conv + desc.off[10];
  const unsigned short* cpv_w  = conv + desc.off[11];
  const unsigned short* cnv_g  = conv + desc.off[12];
  const unsigned short* cnv_b  = conv + desc.off[13];
  const unsigned short* crph   = conv + desc.off[14];
  const unsigned short* crpw   = conv + desc.off[15];
  const unsigned short* crpt   = conv + desc.off[16];

  k_convert<<<dim3(592, 17), 256, 0, stream>>>(desc, conv, flagp, (const unsigned int*)d_in[0]);
  k_qkv_q <<<dim3(1569), 256, 0, stream>>>(cx, cqkv_w, cqkv_b, q_raw);
  k_qkv_kv<<<dim3(201), 256, 0, stream>>>(cx, cqkv_w, cqkv_b, kc, vc, kcls, vcls);
  k_poolq<<<dim3(28, 8, 8), 384, 0, stream>>>(q_raw, cpq_w, cnq_g, cnq_b, q_pool);
  k_poolkv<<<dim3(8*416, 2), 128, 0, stream>>>(kc, vc, kcls, vcls, cpk_w, cnk_g, cnk_b, cpv_w, cnv_g, cnv_b, k_pool, v_t);
  k_rel  <<<dim3(99, 8), 256, 0, stream>>>(q_pool, crph, crpw, crpt, Trel);
  k_attn <<<dim3(99, 8), 256, 0, stream>>>(q_pool, k_pool, v_t, Trel, a_out);
  k_proj <<<dim3(393, 3), 256, 0, stream>>>(a_out, cproj_w, cproj_b, d_out, flagp);
}

// Round 9
// 306.013 us; speedup vs baseline: 4.8970x; 1.0998x over previous
//
#include <hip/hip_runtime.h>
#include <hip/hip_bf16.h>

typedef short short8 __attribute__((ext_vector_type(8)));
typedef float floatx4 __attribute__((ext_vector_type(4)));
typedef float floatx4v __attribute__((ext_vector_type(4)));

#define SCALE_F 0.10206207261596575f

static __device__ __forceinline__ float b2f(unsigned short u){
  unsigned int v = ((unsigned int)u) << 16; float f;
  __builtin_memcpy(&f, &v, 4); return f;
}
static __device__ __forceinline__ unsigned short f2b(float f){
  __hip_bfloat16 h = __float2bfloat16(f);
  unsigned short u; __builtin_memcpy(&u, &h, 2); return u;
}
static __device__ __forceinline__ int map20(int i){
  return (i < 2) ? i : 7 + ((i-2)/3)*8 + ((i-2)%3);
}

struct ConvDesc {
  const void* src[17];
  long long off[17];
  int count[17];
};

// ---------------- K0: dtype detect + convert SMALL tensors (1..16) to bf16 ------------
__global__ __launch_bounds__(256) void k_convert(ConvDesc d, unsigned short* dst_base,
                                                 int* flagp, const unsigned int* xprobe)
{
  __shared__ int sflag;
  if (threadIdx.x < 64){
    unsigned int w = xprobe[1024 + threadIdx.x];
    int e = (w >> 7) & 0xFF;
    int pl = (e >= 90 && e <= 140) ? 1 : 0;
    unsigned long long m = __ballot(pl);
    if (threadIdx.x == 0){
      sflag = (__popcll(m) < 40) ? 1 : 0;   // 1 = inputs are fp32
      if (blockIdx.x == 0 && blockIdx.y == 0) *flagp = sflag;
    }
  }
  __syncthreads();
  const int flag = sflag;
  const int t = blockIdx.y + 1;             // skip x (tensor 0)
  const int cnt = d.count[t];
  unsigned short* dst = dst_base + d.off[t];
  const float* sf = (const float*)d.src[t];
  const unsigned short* su = (const unsigned short*)d.src[t];
  for (int i = blockIdx.x*blockDim.x + threadIdx.x; i < cnt; i += gridDim.x*blockDim.x){
    dst[i] = flag ? f2b(sf[i]) : su[i];
  }
}

// load one 16-row A-fragment triple from x (flag-dependent dtype)
static __device__ __forceinline__ void load_x_frag(
    const void* xr_, int flag, size_t elem_off, short8& a0, short8& a1, short8& a2)
{
  if (flag){
    const float* xr = (const float*)xr_ + elem_off;
    floatx4v f0 = *(const floatx4v*)(xr),      f1 = *(const floatx4v*)(xr+4);
    floatx4v f2 = *(const floatx4v*)(xr+32),   f3 = *(const floatx4v*)(xr+36);
    floatx4v f4 = *(const floatx4v*)(xr+64),   f5 = *(const floatx4v*)(xr+68);
    #pragma unroll
    for (int j = 0; j < 4; ++j){
      a0[j] = (short)f2b(f0[j]); a0[j+4] = (short)f2b(f1[j]);
      a1[j] = (short)f2b(f2[j]); a1[j+4] = (short)f2b(f3[j]);
      a2[j] = (short)f2b(f4[j]); a2[j+4] = (short)f2b(f5[j]);
    }
  } else {
    const unsigned short* xr = (const unsigned short*)xr_ + elem_off;
    a0 = *(const short8*)(xr);
    a1 = *(const short8*)(xr + 32);
    a2 = *(const short8*)(xr + 64);
  }
}

// ---------------- K1a: Q-columns GEMM (all tokens, cols 0..191) ----------------
__global__ __launch_bounds__(256) void k_qkv_q(
    const void* __restrict__ x, const unsigned short* __restrict__ w,
    const unsigned short* __restrict__ bias, unsigned short* __restrict__ qr,
    const int* __restrict__ flagp)
{
  const int flag = *flagp;
  const int lane = threadIdx.x & 63;
  const int wv = threadIdx.x >> 6;
  const int kq = (lane >> 4) * 8;
  const int m_base = blockIdx.x * 64 + wv * 16;

  int ma = m_base + (lane & 15); if (ma > 100355) ma = 100355;
  short8 a0, a1, a2;
  load_x_frag(x, flag, (size_t)ma*96 + kq, a0, a1, a2);

  size_t base0[4];
  int mrow[4];
  #pragma unroll
  for (int r = 0; r < 4; ++r){
    int m = m_base + (lane >> 4)*4 + r;
    mrow[r] = m;
    int bb = m / 25089; int n = m - bb*25089;
    base0[r] = ((size_t)(bb*2)*25089 + n)*96;
  }

  #pragma unroll
  for (int ct = 0; ct < 12; ++ct){
    int col = ct*16 + (lane & 15);
    const unsigned short* wrow = w + col*96 + kq;
    short8 b0 = *(const short8*)(wrow);
    short8 b1 = *(const short8*)(wrow + 32);
    short8 b2 = *(const short8*)(wrow + 64);
    float bv = b2f(bias[col]);
    floatx4 acc = {0.f,0.f,0.f,0.f};
    acc = __builtin_amdgcn_mfma_f32_16x16x32_bf16(a0, b0, acc, 0,0,0);
    acc = __builtin_amdgcn_mfma_f32_16x16x32_bf16(a1, b1, acc, 0,0,0);
    acc = __builtin_amdgcn_mfma_f32_16x16x32_bf16(a2, b2, acc, 0,0,0);
    const int head = ct / 6;
    const int dstat = (ct % 6) * 16;
    size_t hoff = (size_t)head * 2408544 + dstat + (lane & 15);
    #pragma unroll
    for (int r = 0; r < 4; ++r){
      if (mrow[r] < 100356) qr[base0[r] + hoff] = f2b(acc[r] + bv);
    }
  }
}

// ---------------- K1b: KV-columns GEMM (gathered tokens; y-half selects K or V) ------
__global__ __launch_bounds__(256) void k_qkv_kv(
    const void* __restrict__ x, const unsigned short* __restrict__ w,
    const unsigned short* __restrict__ bias,
    unsigned short* __restrict__ kc, unsigned short* __restrict__ vc,
    unsigned short* __restrict__ kcls, unsigned short* __restrict__ vcls,
    const int* __restrict__ flagp)
{
  const int flag = *flagp;
  const int isv = blockIdx.y;
  const int lane = threadIdx.x & 63;
  const int wv = threadIdx.x >> 6;
  const int kq = (lane >> 4) * 8;
  const int quad = lane >> 4;
  const int col_l = lane & 15;
  const int rbase = blockIdx.x * 64 + wv * 16;

  int rhoA = rbase + col_l; if (rhoA > 12803) rhoA = 12803;
  int bA, nA;
  if (rhoA < 4){ bA = rhoA; nA = 0; }
  else {
    int rp = rhoA - 4;
    bA = rp / 3200; int rem = rp - bA*3200;
    int t = rem / 400; int s = rem - t*400;
    int ry = s / 20, rx = s - ry*20;
    nA = 1 + (t*56 + map20(ry))*56 + map20(rx);
  }
  short8 a0, a1, a2;
  load_x_frag(x, flag, ((size_t)bA*25089 + nA)*96 + kq, a0, a1, a2);

  int isCls[4], bI[4], baseI[4], valid[4];
  #pragma unroll
  for (int r = 0; r < 4; ++r){
    int rho = rbase + quad*4 + r;
    valid[r] = (rho < 12804);
    if (rho > 12803) rho = 12803;
    if (rho < 4){ isCls[r] = 1; bI[r] = rho; baseI[r] = 0; }
    else {
      int rp = rho - 4;
      int b = rp / 3200; int rem = rp - b*3200;
      int t = rem / 400; int s = rem - t*400;
      int ry = s / 20, rx = s - ry*20;
      isCls[r] = 0; bI[r] = b;
      baseI[r] = (((b*8 + t)*20 + ry)*20 + rx)*192;
    }
  }

  unsigned short* buf  = isv ? vc : kc;
  unsigned short* bufc = isv ? vcls : kcls;
  #pragma unroll
  for (int ct = 0; ct < 12; ++ct){
    const int col = 192 + (isv*12 + ct)*16 + col_l;
    const unsigned short* wrow = w + col*96 + kq;
    short8 b0 = *(const short8*)(wrow);
    short8 b1 = *(const short8*)(wrow + 32);
    short8 b2 = *(const short8*)(wrow + 64);
    float bv = b2f(bias[col]);
    floatx4 acc = {0.f,0.f,0.f,0.f};
    acc = __builtin_amdgcn_mfma_f32_16x16x32_bf16(a0, b0, acc, 0,0,0);
    acc = __builtin_amdgcn_mfma_f32_16x16x32_bf16(a1, b1, acc, 0,0,0);
    acc = __builtin_amdgcn_mfma_f32_16x16x32_bf16(a2, b2, acc, 0,0,0);
    const int head = ct / 6;
    const int dstat = (ct % 6) * 16;
    #pragma unroll
    for (int r = 0; r < 4; ++r){
      if (valid[r]){
        float o = acc[r] + bv;
        if (isCls[r]) bufc[(bI[r]*2 + head)*96 + dstat + col_l] = f2b(o);
        else          buf[baseI[r] + head*96 + dstat + col_l]   = f2b(o);
      }
    }
  }
}

// ---------------- K2: q pooling (stride 1,2,2) + LN ----------
__global__ __launch_bounds__(384) void k_poolq(
    const unsigned short* __restrict__ qr, const unsigned short* __restrict__ cw,
    const unsigned short* __restrict__ g, const unsigned short* __restrict__ bta,
    unsigned short* __restrict__ qp)
{
  __shared__ float wlds[27*96];
  __shared__ float gls[96], bls[96];
  __shared__ float ls1[29*12], ls2[29*12];
  __shared__ float lmean[29], linvs[29];

  const int y  = blockIdx.x;
  const int t  = blockIdx.y;
  const int bh = blockIdx.z;
  const int tid = threadIdx.x;
  const bool has_cls = (y == 0 && t == 0);
  const unsigned short* base = qr + (size_t)bh*2408544;

  for (int idx = tid; idx < 27*96; idx += 384){
    int tap = idx / 96, d = idx - tap*96;
    wlds[idx] = b2f(cw[d*27 + tap]);
  }
  for (int idx = tid; idx < 96; idx += 384){
    gls[idx] = b2f(g[idx]); bls[idx] = b2f(bta[idx]);
  }
  __syncthreads();

  const int x = tid / 12, dg = tid - x*12;
  float val[8] = {0,0,0,0,0,0,0,0};

  if (x < 28){
    #pragma unroll
    for (int dt = 0; dt < 3; ++dt){
      int tt = t + dt - 1; if (tt < 0 || tt >= 8) continue;
      #pragma unroll
      for (int dy = 0; dy < 3; ++dy){
        int yy = 2*y + dy - 1; if (yy < 0 || yy >= 56) continue;
        #pragma unroll
        for (int dx = 0; dx < 3; ++dx){
          int xv = 2*x + dx - 1; if (xv < 0 || xv >= 56) continue;
          const int tap = (dt*3+dy)*3+dx;
          short8 v = *(const short8*)(base + (size_t)(1 + (tt*56 + yy)*56 + xv)*96 + dg*8);
          const float* wr = wlds + tap*96 + dg*8;
          #pragma unroll
          for (int j = 0; j < 8; ++j) val[j] += b2f((unsigned short)v[j]) * wr[j];
        }
      }
    }
    float s1 = 0.f, s2 = 0.f;
    #pragma unroll
    for (int j = 0; j < 8; ++j){ s1 += val[j]; s2 += val[j]*val[j]; }
    ls1[x*12+dg] = s1; ls2[x*12+dg] = s2;
  } else if (has_cls && tid >= 348 && tid < 360){
    int cdg = tid - 348;
    short8 v = *(const short8*)(base + cdg*8);
    float s1 = 0.f, s2 = 0.f;
    #pragma unroll
    for (int j = 0; j < 8; ++j){ val[j] = b2f((unsigned short)v[j]); s1 += val[j]; s2 += val[j]*val[j]; }
    ls1[28*12+cdg] = s1; ls2[28*12+cdg] = s2;
  }
  __syncthreads();

  if (tid < 28 || (tid == 28 && has_cls)){
    float s1 = 0.f, s2 = 0.f;
    #pragma unroll
    for (int k = 0; k < 12; ++k){ s1 += ls1[tid*12+k]; s2 += ls2[tid*12+k]; }
    float mean = s1 * (1.f/96.f);
    float var  = s2 * (1.f/96.f) - mean*mean;
    lmean[tid] = mean; linvs[tid] = rsqrtf(var + 1e-5f);
  }
  __syncthreads();

  if (x < 28){
    float mean = lmean[x], inv = linvs[x];
    int tok = 1 + (t*28 + y)*28 + x;
    short8 o;
    #pragma unroll
    for (int j = 0; j < 8; ++j)
      o[j] = (short)f2b((val[j] - mean)*inv*gls[dg*8+j] + bls[dg*8+j]);
    *(short8*)(qp + ((size_t)bh*6273 + tok)*96 + dg*8) = o;
  } else if (has_cls && tid >= 348 && tid < 360){
    int cdg = tid - 348;
    float mean = lmean[28], inv = linvs[28];
    short8 o;
    #pragma unroll
    for (int j = 0; j < 8; ++j)
      o[j] = (short)f2b((val[j] - mean)*inv*gls[cdg*8+j] + bls[cdg*8+j]);
    *(short8*)(qp + (size_t)bh*6273*96 + cdg*8) = o;
  }
}

// ---------------- K3: k/v pooling from compact buffers + LN; v transposed ----------
__global__ __launch_bounds__(128) void k_poolkv(
    const unsigned short* __restrict__ kc, const unsigned short* __restrict__ vc,
    const unsigned short* __restrict__ kcls, const unsigned short* __restrict__ vcls,
    const unsigned short* __restrict__ cwk, const unsigned short* __restrict__ gk, const unsigned short* __restrict__ bk,
    const unsigned short* __restrict__ cwv, const unsigned short* __restrict__ gv, const unsigned short* __restrict__ bv,
    unsigned short* __restrict__ kp, unsigned short* __restrict__ vt)
{
  const int bid = blockIdx.x;
  const int isv = blockIdx.y;
  const int bh = bid / 416; const int key = bid - bh*416;
  const int d = threadIdx.x;
  if (key >= 393){
    if (d < 96){
      if (isv == 0) kp[((size_t)bh*416 + key)*96 + d] = 0;
      else          vt[((size_t)bh*96 + d)*416 + key] = 0;
    }
    return;
  }
  const int b = bh >> 1, head = bh & 1;
  const unsigned short* buf  = isv ? vc : kc;
  const unsigned short* bufc = isv ? vcls : kcls;
  const unsigned short* cw = (isv == 0) ? cwk : cwv;
  const unsigned short* g  = (isv == 0) ? gk : gv;
  const unsigned short* bt = (isv == 0) ? bk : bv;
  float val = 0.f;
  if (d < 96){
    if (key == 0) val = b2f(bufc[bh*96 + d]);
    else {
      int s = key - 1; int t = s / 49; int r2 = s - t*49; int y = r2 / 7; int xx = r2 - y*7;
      const unsigned short* wr = cw + d*27;
      float sum = 0.f;
      #pragma unroll
      for (int dt = 0; dt < 3; ++dt){
        int tt = t + dt - 1; if (tt < 0 || tt >= 8) continue;
        #pragma unroll
        for (int dy = 0; dy < 3; ++dy){
          if (y == 0 && dy == 0) continue;
          int ry = (y == 0) ? (dy - 1) : 2 + 3*(y-1) + dy;
          #pragma unroll
          for (int dx = 0; dx < 3; ++dx){
            if (xx == 0 && dx == 0) continue;
            int rx = (xx == 0) ? (dx - 1) : 2 + 3*(xx-1) + dx;
            sum += b2f(buf[(((b*8 + tt)*20 + ry)*20 + rx)*192 + head*96 + d]) * b2f(wr[(dt*3+dy)*3+dx]);
          }
        }
      }
      val = sum;
    }
  }
  __shared__ float r1[128], r2s[128];
  r1[threadIdx.x] = (d < 96) ? val : 0.f;
  r2s[threadIdx.x] = (d < 96) ? val*val : 0.f;
  __syncthreads();
  for (int off = 64; off > 0; off >>= 1){
    if ((int)threadIdx.x < off){ r1[threadIdx.x] += r1[threadIdx.x+off]; r2s[threadIdx.x] += r2s[threadIdx.x+off]; }
    __syncthreads();
  }
  if (d < 96){
    float mean = r1[0] * (1.f/96.f);
    float var  = r2s[0] * (1.f/96.f) - mean*mean;
    float inv = rsqrtf(var + 1e-5f);
    float o = (val - mean)*inv*b2f(g[d]) + b2f(bt[d]);
    if (isv == 0) kp[((size_t)bh*416 + key)*96 + d] = f2b(o);
    else          vt[((size_t)bh*96 + d)*416 + key] = f2b(o);
  }
}

// ---------------- K3b: rel-pos compact table: Trel[bh][q][24] float ----------------
__global__ __launch_bounds__(256) void k_rel(
    const unsigned short* __restrict__ qp,
    const unsigned short* __restrict__ rph, const unsigned short* __restrict__ rpw,
    const unsigned short* __restrict__ rpt,
    float* __restrict__ Trel)
{
  const int lane = threadIdx.x & 63;
  const int wv = threadIdx.x >> 6;
  const int bh = blockIdx.y;
  const int q0 = blockIdx.x*64 + wv*16;
  const int kq = (lane >> 4) * 8;
  const int quad = lane >> 4;
  const int col_l = lane & 15;

  const unsigned short* qbase = qp + (size_t)bh*6273*96;
  int qa = q0 + col_l; if (qa > 6272) qa = 6272;
  const unsigned short* qrow = qbase + (size_t)qa*96 + kq;
  short8 a0 = *(const short8*)(qrow);
  short8 a1 = *(const short8*)(qrow + 32);
  short8 a2 = *(const short8*)(qrow + 64);

  int yq[4], xq[4], tq[4], liv[4];
  #pragma unroll
  for (int r = 0; r < 4; ++r){
    int gq = q0 + quad*4 + r;
    liv[r] = (gq >= 1 && gq <= 6272);
    int s = (gq >= 1) ? gq - 1 : 0;
    tq[r] = s / 784; int r2 = s - tq[r]*784; yq[r] = r2 / 28; xq[r] = r2 - yq[r]*28;
  }
  float* Tb = Trel + (size_t)bh*6273*24;

  #pragma unroll
  for (int ct = 0; ct < 8; ++ct){
    int c = ct*16 + col_l;
    const unsigned short* rrow;
    if (c < 55)       rrow = rph + (size_t)c*96;
    else if (c < 110) rrow = rpw + (size_t)(c-55)*96;
    else { int ci = c-110; if (ci > 14) ci = 14; rrow = rpt + (size_t)ci*96; }
    rrow += kq;
    short8 b0 = *(const short8*)(rrow);
    short8 b1 = *(const short8*)(rrow + 32);
    short8 b2 = *(const short8*)(rrow + 64);
    floatx4 acc = {0.f,0.f,0.f,0.f};
    acc = __builtin_amdgcn_mfma_f32_16x16x32_bf16(a0, b0, acc, 0,0,0);
    acc = __builtin_amdgcn_mfma_f32_16x16x32_bf16(a1, b1, acc, 0,0,0);
    acc = __builtin_amdgcn_mfma_f32_16x16x32_bf16(a2, b2, acc, 0,0,0);
    #pragma unroll
    for (int r = 0; r < 4; ++r){
      int gq = q0 + quad*4 + r;
      if (!liv[r] || gq > 6272) continue;
      float* Tq = Tb + (size_t)gq*24;
      if (c < 55){
        int u = yq[r] + 24 - c;
        if (u >= 0 && u <= 24 && (u & 3) == 0) Tq[u >> 2] = acc[r];
      } else if (c < 110){
        int u = xq[r] + 24 - (c - 55);
        if (u >= 0 && u <= 24 && (u & 3) == 0) Tq[8 + (u >> 2)] = acc[r];
      } else if (c < 125){
        int u = tq[r] + 7 - (c - 110);
        if (u >= 0 && u <= 7) Tq[16 + u] = acc[r];
      }
    }
  }
}

// ---------------- K4: fused attention — 2 independent waves/block, barrier-free ------
// Each wave: 16 queries end-to-end; single-pass softmax; 25 key tiles (tile 25 = pad,
// P zeroed); per-wave rel + P strips in LDS; coords computed in registers.
#define PSTR 424
__global__ __launch_bounds__(128) void k_attn(
    const unsigned short* __restrict__ qp, const unsigned short* __restrict__ kp,
    const unsigned short* __restrict__ vt, const float* __restrict__ Trel,
    unsigned short* __restrict__ ao)
{
  __shared__ unsigned short P[2][16*PSTR];   // 27.1 KB
  __shared__ float rel[2][16*24];            // 3 KB

  const int bh = blockIdx.y;
  const int bb = bh >> 1, head = bh & 1;
  const int tid = threadIdx.x;
  const int lane = tid & 63;
  const int wv = tid >> 6;
  const int q0 = (blockIdx.x*2 + wv)*16;

  const unsigned short* qbase = qp + (size_t)bh*6273*96;
  const unsigned short* kbase = kp + (size_t)bh*416*96;
  const unsigned short* vbase = vt + (size_t)bh*96*416;

  // per-wave rel staging (no barrier needed: same-wave LDS ordering)
  float* relw = &rel[wv][0];
  #pragma unroll
  for (int it = 0; it < 2; ++it){
    int idx = lane + it*64;                 // 0..95
    if (idx < 96){
      int row = idx / 6, seg = idx - row*6;
      int gq = q0 + row; if (gq > 6272) gq = 6272;
      *(floatx4v*)(relw + row*24 + seg*4) =
        *(const floatx4v*)(Trel + ((size_t)bh*6273 + gq)*24 + seg*4);
    }
  }

  const int col = lane & 15;
  const int quad = lane >> 4;
  const int kq = quad * 8;

  short8 a0, a1, a2;
  {
    int qa = q0 + col; if (qa > 6272) qa = 6272;
    const unsigned short* qrow = qbase + (size_t)qa*96 + kq;
    a0 = *(const short8*)(qrow);
    a1 = *(const short8*)(qrow + 32);
    a2 = *(const short8*)(qrow + 64);
  }

  int liv[4];
  const float* Tm[4];
  #pragma unroll
  for (int r = 0; r < 4; ++r){
    int gq = q0 + quad*4 + r;
    liv[r] = (gq >= 1);
    Tm[r] = relw + (quad*4 + r)*24;
  }

  // QK^T over 25 tiles with fused rel/scale/max
  floatx4 acc[25];
  float mx[4] = {-1e30f,-1e30f,-1e30f,-1e30f};
  #pragma unroll
  for (int t = 0; t < 25; ++t){
    const unsigned short* krow = kbase + (size_t)(t*16 + col)*96 + kq;
    short8 b0 = *(const short8*)(krow);
    short8 b1 = *(const short8*)(krow + 32);
    short8 b2 = *(const short8*)(krow + 64);
    floatx4 a = {0.f,0.f,0.f,0.f};
    a = __builtin_amdgcn_mfma_f32_16x16x32_bf16(a0, b0, a, 0,0,0);
    a = __builtin_amdgcn_mfma_f32_16x16x32_bf16(a1, b1, a, 0,0,0);
    a = __builtin_amdgcn_mfma_f32_16x16x32_bf16(a2, b2, a, 0,0,0);
    const int key = t*16 + col;
    const bool validk = (t < 24) || (col <= 8);   // keys < 393
    int kt = 0, ky = 0, kx = 0;
    if (key >= 1){
      int ks = key - 1; kt = ks / 49; int krm = ks - kt*49; ky = krm / 7; kx = krm - ky*7;
    }
    #pragma unroll
    for (int r = 0; r < 4; ++r){
      float s;
      if (!validk) s = -1e30f;
      else {
        s = a[r] * SCALE_F;
        if (key >= 1 && liv[r])
          s += Tm[r][ky] + Tm[r][8 + kx] + Tm[r][16 + kt];
      }
      a[r] = s;
      mx[r] = fmaxf(mx[r], s);
    }
    acc[t] = a;
  }
  #pragma unroll
  for (int r = 0; r < 4; ++r){
    #pragma unroll
    for (int o = 1; o < 16; o <<= 1) mx[r] = fmaxf(mx[r], __shfl_xor(mx[r], o, 64));
  }
  float sum[4] = {0.f,0.f,0.f,0.f};
  #pragma unroll
  for (int t = 0; t < 25; ++t){
    #pragma unroll
    for (int r = 0; r < 4; ++r){
      float e = __expf(acc[t][r] - mx[r]);
      acc[t][r] = e; sum[r] += e;
    }
  }
  float linv4[4];
  #pragma unroll
  for (int r = 0; r < 4; ++r){
    #pragma unroll
    for (int o = 1; o < 16; o <<= 1) sum[r] += __shfl_xor(sum[r], o, 64);
    linv4[r] = 1.f / sum[r];
  }

  // write P strip (bf16, unnormalized); zero the pad tile (keys 400..415)
  unsigned short* Pw = &P[wv][0];
  #pragma unroll
  for (int t = 0; t < 25; ++t){
    #pragma unroll
    for (int r = 0; r < 4; ++r)
      Pw[(quad*4 + r)*PSTR + t*16 + col] = f2b(acc[t][r]);
  }
  #pragma unroll
  for (int r = 0; r < 4; ++r)
    Pw[(quad*4 + r)*PSTR + 400 + col] = 0;

  // PV (same-wave LDS ordering; no barrier)
  short8 pf[13];
  #pragma unroll
  for (int s = 0; s < 13; ++s)
    pf[s] = *(const short8*)(Pw + col*PSTR + s*32 + kq);

  #pragma unroll
  for (int dt = 0; dt < 6; ++dt){
    const int dd = dt*16 + col;
    const unsigned short* vrow = vbase + (size_t)dd*416 + kq;
    floatx4 o = {0.f,0.f,0.f,0.f};
    #pragma unroll
    for (int s = 0; s < 13; ++s){
      short8 vf = *(const short8*)(vrow + s*32);
      o = __builtin_amdgcn_mfma_f32_16x16x32_bf16(pf[s], vf, o, 0,0,0);
    }
    #pragma unroll
    for (int r = 0; r < 4; ++r){
      int gq = q0 + quad*4 + r;
      if (gq <= 6272){
        float val = o[r] * linv4[r] + b2f(qbase[(size_t)gq*96 + dd]);
        ao[((size_t)bb*6273 + gq)*192 + head*96 + dd] = f2b(val);
      }
    }
  }
}

// ---------------- K5: proj GEMM (flag-aware output dtype) ----------------
__global__ __launch_bounds__(256) void k_proj(
    const unsigned short* __restrict__ ao, const unsigned short* __restrict__ w,
    const unsigned short* __restrict__ bias, void* __restrict__ out, const int* __restrict__ flagp)
{
  const int flag = *flagp;
  const int lane = threadIdx.x & 63;
  const int wv = threadIdx.x >> 6;
  const int c = blockIdx.y*64 + wv*16 + (lane & 15);
  const int kq = (lane >> 4) * 8;
  short8 bfr[6];
  const unsigned short* wrow = w + c*192 + kq;
  #pragma unroll
  for (int s = 0; s < 6; ++s) bfr[s] = *(const short8*)(wrow + 32*s);
  float bv = b2f(bias[c]);
  const int m_base = blockIdx.x * 64;
  for (int i = 0; i < 4; ++i){
    int mt = m_base + i*16;
    int ma = mt + (lane & 15); if (ma > 25091) ma = 25091;
    const unsigned short* arow = ao + (size_t)ma*192 + kq;
    floatx4 acc = {0.f,0.f,0.f,0.f};
    #pragma unroll
    for (int s = 0; s < 6; ++s){
      short8 a = *(const short8*)(arow + 32*s);
      acc = __builtin_amdgcn_mfma_f32_16x16x32_bf16(a, bfr[s], acc, 0,0,0);
    }
    #pragma unroll
    for (int r = 0; r < 4; ++r){
      int m = mt + (lane >> 4)*4 + r;
      if (m < 25092){
        float o = acc[r] + bv;
        if (flag) ((float*)out)[(size_t)m*192 + c] = o;
        else      ((unsigned short*)out)[(size_t)m*192 + c] = f2b(o);
      }
    }
  }
}

extern "C" void kernel_launch(void* const* d_in, const int* in_sizes, int n_in,
                              void* d_out, int out_size, void* d_ws, size_t ws_size,
                              hipStream_t stream)
{
  char* p = (char*)d_ws;
  int* flagp = (int*)p; p += 16;
  unsigned short* conv = (unsigned short*)p;

  ConvDesc desc;
  long long cum = 0;
  for (int i = 0; i < 17; ++i){
    desc.src[i] = d_in[i];
    desc.off[i] = cum;
    desc.count[i] = in_sizes[i];
    cum += in_sizes[i];
  }
  p += (size_t)cum * 2;

  unsigned short* q_raw  = (unsigned short*)p; p += (size_t)19268352*2;
  unsigned short* kc     = (unsigned short*)p; p += (size_t)2457600*2;
  unsigned short* vc     = (unsigned short*)p; p += (size_t)2457600*2;
  unsigned short* kcls   = (unsigned short*)p; p += (size_t)768*2;
  unsigned short* vcls   = (unsigned short*)p; p += (size_t)768*2;
  unsigned short* q_pool = (unsigned short*)p; p += (size_t)4817664*2;
  unsigned short* k_pool = (unsigned short*)p; p += (size_t)319488*2;
  unsigned short* v_t    = (unsigned short*)p; p += (size_t)319488*2;
  float*          Trel   = (float*)p;         p += (size_t)8*6273*24*4;
  unsigned short* a_out  = q_raw;   // q_raw dead after k_poolq

  const unsigned short* cqkv_w = conv + desc.off[1];
  const unsigned short* cqkv_b = conv + desc.off[2];
  const unsigned short* cproj_w= conv + desc.off[3];
  const unsigned short* cproj_b= conv + desc.off[4];
  const unsigned short* cpq_w  = conv + desc.off[5];
  const unsigned short* cnq_g  = conv + desc.off[6];
  const unsigned short* cnq_b  = conv + desc.off[7];
  const unsigned short* cpk_w  = conv + desc.off[8];
  const unsigned short* cnk_g  = conv + desc.off[9];
  const unsigned short* cnk_b  = conv + desc.off[10];
  const unsigned short* cpv_w  = conv + desc.off[11];
  const unsigned short* cnv_g  = conv + desc.off[12];
  const unsigned short* cnv_b  = conv + desc.off[13];
  const unsigned short* crph   = conv + desc.off[14];
  const unsigned short* crpw   = conv + desc.off[15];
  const unsigned short* crpt   = conv + desc.off[16];

  k_convert<<<dim3(16, 16), 256, 0, stream>>>(desc, conv, flagp, (const unsigned int*)d_in[0]);
  k_qkv_q <<<dim3(1569), 256, 0, stream>>>(d_in[0], cqkv_w, cqkv_b, q_raw, flagp);
  k_qkv_kv<<<dim3(201, 2), 256, 0, stream>>>(d_in[0], cqkv_w, cqkv_b, kc, vc, kcls, vcls, flagp);
  k_poolq<<<dim3(28, 8, 8), 384, 0, stream>>>(q_raw, cpq_w, cnq_g, cnq_b, q_pool);
  k_poolkv<<<dim3(8*416, 2), 128, 0, stream>>>(kc, vc, kcls, vcls, cpk_w, cnk_g, cnk_b, cpv_w, cnv_g, cnv_b, k_pool, v_t);
  k_rel  <<<dim3(99, 8), 256, 0, stream>>>(q_pool, crph, crpw, crpt, Trel);
  k_attn <<<dim3(197, 8), 128, 0, stream>>>(q_pool, k_pool, v_t, Trel, a_out);
  k_proj <<<dim3(393, 3), 256, 0, stream>>>(a_out, cproj_w, cproj_b, d_out, flagp);
}